// Round 1
// baseline (1349.637 us; speedup 1.0000x reference)
//
#include <hip/hip_runtime.h>
#include <hip/hip_bf16.h>
#include <cstdint>

#define D_MODEL  1024
#define D_INNER  2048
#define D_STATE  16
#define DT_RANK  64
#define KERW     4
#define BATCH    2
#define SEQ      1024
#define NTOK     (BATCH * SEQ)

__device__ __forceinline__ float siluf(float x) {
    return x / (1.f + __expf(-x));
}

// ---------------------------------------------------------------------------
// Generic fp32 GEMM: C[M,N] = A[M,K] @ B[K,N]  (row-major, arbitrary ld)
// 64x64 tile, 16 k-slice, 256 threads, 4x4 per thread.
// Optional epilogue: + bias[col], softplus.
// Requires K % 16 == 0, lda/ldb multiples of 4 (true for all our shapes).
// ---------------------------------------------------------------------------
template<bool BIAS, bool SOFTPLUS>
__global__ __launch_bounds__(256)
void gemm_f32(const float* __restrict__ A, const float* __restrict__ B,
              const float* __restrict__ bias, float* __restrict__ C,
              int M, int N, int K, int lda, int ldb, int ldc)
{
    __shared__ float As[16][68];   // [k][m]
    __shared__ float Bs[16][68];   // [k][n]
    const int tid = threadIdx.x;
    const int tx = tid & 15, ty = tid >> 4;
    const int bm = blockIdx.y * 64, bn = blockIdx.x * 64;

    float acc[4][4] = {};

    const int ar  = tid >> 2;          // 0..63  A row within tile
    const int ac4 = (tid & 3) << 2;    // 0,4,8,12  A k-col
    const int bkr = tid >> 4;          // 0..15  B k-row
    const int bc4 = (tid & 15) << 2;   // 0..60  B col

    for (int k0 = 0; k0 < K; k0 += 16) {
        float4 av = make_float4(0.f, 0.f, 0.f, 0.f);
        {
            int row = bm + ar;
            if (row < M)
                av = *(const float4*)(A + (size_t)row * lda + (k0 + ac4));
        }
        As[ac4 + 0][ar] = av.x; As[ac4 + 1][ar] = av.y;
        As[ac4 + 2][ar] = av.z; As[ac4 + 3][ar] = av.w;

        float4 bv = make_float4(0.f, 0.f, 0.f, 0.f);
        {
            int col = bn + bc4;
            const float* bp = B + (size_t)(k0 + bkr) * ldb + col;
            if (col + 3 < N) {
                bv = *(const float4*)bp;
            } else {
                if (col + 0 < N) bv.x = bp[0];
                if (col + 1 < N) bv.y = bp[1];
                if (col + 2 < N) bv.z = bp[2];
                if (col + 3 < N) bv.w = bp[3];
            }
        }
        Bs[bkr][bc4 + 0] = bv.x; Bs[bkr][bc4 + 1] = bv.y;
        Bs[bkr][bc4 + 2] = bv.z; Bs[bkr][bc4 + 3] = bv.w;

        __syncthreads();

        #pragma unroll
        for (int kk = 0; kk < 16; ++kk) {
            float a[4], b[4];
            #pragma unroll
            for (int i = 0; i < 4; ++i) a[i] = As[kk][ty * 4 + i];
            #pragma unroll
            for (int j = 0; j < 4; ++j) b[j] = Bs[kk][tx * 4 + j];
            #pragma unroll
            for (int i = 0; i < 4; ++i)
                #pragma unroll
                for (int j = 0; j < 4; ++j)
                    acc[i][j] = fmaf(a[i], b[j], acc[i][j]);
        }
        __syncthreads();
    }

    #pragma unroll
    for (int i = 0; i < 4; ++i) {
        int row = bm + ty * 4 + i;
        if (row >= M) continue;
        #pragma unroll
        for (int j = 0; j < 4; ++j) {
            int col = bn + tx * 4 + j;
            if (col >= N) continue;
            float v = acc[i][j];
            if (BIAS) v += bias[col];
            if (SOFTPLUS) v = (v > 20.f) ? v : log1pf(__expf(v));
            C[(size_t)row * ldc + col] = v;
        }
    }
}

// ---------------------------------------------------------------------------
// Depthwise causal conv (K=4) + bias + SiLU.
// Reads x = xz[:, 0:D_INNER] (ld 2*D_INNER), writes u[t, d] token-major.
// ---------------------------------------------------------------------------
__global__ __launch_bounds__(256)
void conv_silu(const float* __restrict__ xz, const float* __restrict__ conv_w,
               const float* __restrict__ conv_b, float* __restrict__ u)
{
    int idx = blockIdx.x * 256 + threadIdx.x;       // over NTOK * D_INNER
    if (idx >= NTOK * D_INNER) return;
    int d = idx & (D_INNER - 1);
    int t = idx >> 11;                               // D_INNER = 2048
    int l = t & (SEQ - 1);
    int b = t >> 10;                                 // SEQ = 1024

    float w0 = conv_w[d * 4 + 0], w1 = conv_w[d * 4 + 1];
    float w2 = conv_w[d * 4 + 2], w3 = conv_w[d * 4 + 3];

    const float* base = xz + (size_t)b * SEQ * (2 * D_INNER) + d;
    float acc = conv_b[d];
    if (l >= 3) acc += w0 * base[(size_t)(l - 3) * (2 * D_INNER)];
    if (l >= 2) acc += w1 * base[(size_t)(l - 2) * (2 * D_INNER)];
    if (l >= 1) acc += w2 * base[(size_t)(l - 1) * (2 * D_INNER)];
    acc += w3 * base[(size_t)l * (2 * D_INNER)];

    u[idx] = siluf(acc);
}

// ---------------------------------------------------------------------------
// Selective scan. 16 lanes per (b,d) pair (one lane per state n).
// Fused: + u*D_skip, * silu(res).  yg may alias delta (in-place, strict
// read-before-write per element).
// ---------------------------------------------------------------------------
__global__ __launch_bounds__(256)
void scan_kernel(const float* delta, const float* __restrict__ u,
                 const float* __restrict__ xdbl, const float* __restrict__ xz,
                 const float* __restrict__ A_log, const float* __restrict__ D_skip,
                 float* yg)
{
    int gid = blockIdx.x * 256 + threadIdx.x;
    int g = gid >> 4;                 // (b,d) group id
    int n = gid & 15;                 // state index
    if (g >= BATCH * D_INNER) return;
    int b = g >> 11;                  // D_INNER = 2048
    int d = g & (D_INNER - 1);

    float An = -__expf(A_log[d * D_STATE + n]);
    float Dd = D_skip[d];
    float h = 0.f;

    const float* dp = delta + (size_t)b * SEQ * D_INNER + d;
    const float* up = u     + (size_t)b * SEQ * D_INNER + d;
    const float* rp = xz    + (size_t)b * SEQ * (2 * D_INNER) + D_INNER + d;
    const float* xb = xdbl  + (size_t)b * SEQ * 96;
    float*       yp = yg    + (size_t)b * SEQ * D_INNER + d;

    for (int l = 0; l < SEQ; ++l) {
        float dt = dp[(size_t)l * D_INNER];
        float ut = up[(size_t)l * D_INNER];
        float Bn = xb[l * 96 + DT_RANK + n];
        float Cn = xb[l * 96 + DT_RANK + D_STATE + n];

        h = __expf(dt * An) * h + dt * Bn * ut;
        float p = h * Cn;
        p += __shfl_xor(p, 1, 16);
        p += __shfl_xor(p, 2, 16);
        p += __shfl_xor(p, 4, 16);
        p += __shfl_xor(p, 8, 16);

        if (n == 0) {
            float res = rp[(size_t)l * (2 * D_INNER)];
            yp[(size_t)l * D_INNER] = (p + ut * Dd) * siluf(res);
        }
    }
}

// ---------------------------------------------------------------------------
extern "C" void kernel_launch(void* const* d_in, const int* in_sizes, int n_in,
                              void* d_out, int out_size, void* d_ws, size_t ws_size,
                              hipStream_t stream)
{
    const float* H      = (const float*)d_in[0];  // [B,L,1024]
    const float* Win    = (const float*)d_in[1];  // [1024, 4096]
    const float* convw  = (const float*)d_in[2];  // [2048,1,4]
    const float* convb  = (const float*)d_in[3];  // [2048]
    const float* xprojw = (const float*)d_in[4];  // [2048, 96]
    const float* dtw    = (const float*)d_in[5];  // [64, 2048]
    const float* dtb    = (const float*)d_in[6];  // [2048]
    const float* Alog   = (const float*)d_in[7];  // [2048, 16]
    const float* Dskip  = (const float*)d_in[8];  // [2048]
    const float* Wout   = (const float*)d_in[9];  // [2048, 1024]
    float* out = (float*)d_out;

    float* ws    = (float*)d_ws;
    float* xz    = ws;                                   // [NTOK, 4096]
    float* u     = xz   + (size_t)NTOK * 4096;           // [NTOK, 2048]
    float* xdbl  = u    + (size_t)NTOK * 2048;           // [NTOK, 96]
    float* delta = xdbl + (size_t)NTOK * 96;             // [NTOK, 2048]
    float* yg    = delta;                                // in-place over delta

    dim3 blk(256);

    // 1) xz = H @ Win   [2048 x 4096 x 1024]
    gemm_f32<false, false><<<dim3(4096 / 64, NTOK / 64), blk, 0, stream>>>(
        H, Win, nullptr, xz, NTOK, 2 * D_INNER, D_MODEL, D_MODEL, 2 * D_INNER, 2 * D_INNER);

    // 2) u = silu(causal_depthwise_conv(x) + b)
    conv_silu<<<(NTOK * D_INNER) / 256, blk, 0, stream>>>(xz, convw, convb, u);

    // 3) x_dbl = u @ x_proj_w   [2048 x 96 x 2048]
    gemm_f32<false, false><<<dim3(2, NTOK / 64), blk, 0, stream>>>(
        u, xprojw, nullptr, xdbl, NTOK, 96, D_INNER, D_INNER, 96, 96);

    // 4) delta = softplus(x_dbl[:, :64] @ dt_proj_w + dt_proj_b)  [2048 x 2048 x 64]
    gemm_f32<true, true><<<dim3(D_INNER / 64, NTOK / 64), blk, 0, stream>>>(
        xdbl, dtw, dtb, delta, NTOK, D_INNER, DT_RANK, 96, D_INNER, D_INNER);

    // 5) selective scan + D-skip + silu(res) gating  (yg aliases delta)
    scan_kernel<<<(BATCH * D_INNER * 16) / 256, blk, 0, stream>>>(
        delta, u, xdbl, xz, Alog, Dskip, yg);

    // 6) out = yg @ Wout   [2048 x 1024 x 2048]
    gemm_f32<false, false><<<dim3(D_MODEL / 64, NTOK / 64), blk, 0, stream>>>(
        yg, Wout, nullptr, out, NTOK, D_MODEL, D_INNER, D_INNER, D_MODEL, D_MODEL);
}

// Round 3
// 766.695 us; speedup vs baseline: 1.7603x; 1.7603x over previous
//
#include <hip/hip_runtime.h>
#include <hip/hip_bf16.h>
#include <cstdint>

#define D_MODEL  1024
#define D_INNER  2048
#define D_STATE  16
#define DT_RANK  64
#define KERW     4
#define BATCH    2
#define SEQ      1024
#define NTOK     (BATCH * SEQ)
#define CHUNKS   16
#define LC       (SEQ / CHUNKS)     // 64 steps per chunk

__device__ __forceinline__ float siluf(float x) {
    return x / (1.f + __expf(-x));
}

// ---------------------------------------------------------------------------
// Generic fp32 GEMM: C[M,N] = A[M,K] @ B[K,N]  (row-major, arbitrary ld)
// 64x64 tile, 16 k-slice, 256 threads, 4x4 per thread.
// ---------------------------------------------------------------------------
template<bool BIAS, bool SOFTPLUS>
__global__ __launch_bounds__(256)
void gemm_f32(const float* __restrict__ A, const float* __restrict__ B,
              const float* __restrict__ bias, float* __restrict__ C,
              int M, int N, int K, int lda, int ldb, int ldc)
{
    __shared__ float As[16][68];   // [k][m]
    __shared__ float Bs[16][68];   // [k][n]
    const int tid = threadIdx.x;
    const int tx = tid & 15, ty = tid >> 4;
    const int bm = blockIdx.y * 64, bn = blockIdx.x * 64;

    float acc[4][4] = {};

    const int ar  = tid >> 2;          // 0..63  A row within tile
    const int ac4 = (tid & 3) << 2;    // 0,4,8,12  A k-col
    const int bkr = tid >> 4;          // 0..15  B k-row
    const int bc4 = (tid & 15) << 2;   // 0..60  B col

    for (int k0 = 0; k0 < K; k0 += 16) {
        float4 av = make_float4(0.f, 0.f, 0.f, 0.f);
        {
            int row = bm + ar;
            if (row < M)
                av = *(const float4*)(A + (size_t)row * lda + (k0 + ac4));
        }
        As[ac4 + 0][ar] = av.x; As[ac4 + 1][ar] = av.y;
        As[ac4 + 2][ar] = av.z; As[ac4 + 3][ar] = av.w;

        float4 bv = make_float4(0.f, 0.f, 0.f, 0.f);
        {
            int col = bn + bc4;
            const float* bp = B + (size_t)(k0 + bkr) * ldb + col;
            if (col + 3 < N) {
                bv = *(const float4*)bp;
            } else {
                if (col + 0 < N) bv.x = bp[0];
                if (col + 1 < N) bv.y = bp[1];
                if (col + 2 < N) bv.z = bp[2];
                if (col + 3 < N) bv.w = bp[3];
            }
        }
        Bs[bkr][bc4 + 0] = bv.x; Bs[bkr][bc4 + 1] = bv.y;
        Bs[bkr][bc4 + 2] = bv.z; Bs[bkr][bc4 + 3] = bv.w;

        __syncthreads();

        #pragma unroll
        for (int kk = 0; kk < 16; ++kk) {
            float a[4], b[4];
            #pragma unroll
            for (int i = 0; i < 4; ++i) a[i] = As[kk][ty * 4 + i];
            #pragma unroll
            for (int j = 0; j < 4; ++j) b[j] = Bs[kk][tx * 4 + j];
            #pragma unroll
            for (int i = 0; i < 4; ++i)
                #pragma unroll
                for (int j = 0; j < 4; ++j)
                    acc[i][j] = fmaf(a[i], b[j], acc[i][j]);
        }
        __syncthreads();
    }

    #pragma unroll
    for (int i = 0; i < 4; ++i) {
        int row = bm + ty * 4 + i;
        if (row >= M) continue;
        #pragma unroll
        for (int j = 0; j < 4; ++j) {
            int col = bn + tx * 4 + j;
            if (col >= N) continue;
            float v = acc[i][j];
            if (BIAS) v += bias[col];
            if (SOFTPLUS) v = (v > 20.f) ? v : log1pf(__expf(v));
            C[(size_t)row * ldc + col] = v;
        }
    }
}

// ---------------------------------------------------------------------------
// Depthwise causal conv (K=4) + bias + SiLU.
// ---------------------------------------------------------------------------
__global__ __launch_bounds__(256)
void conv_silu(const float* __restrict__ xz, const float* __restrict__ conv_w,
               const float* __restrict__ conv_b, float* __restrict__ u)
{
    int idx = blockIdx.x * 256 + threadIdx.x;       // over NTOK * D_INNER
    if (idx >= NTOK * D_INNER) return;
    int d = idx & (D_INNER - 1);
    int t = idx >> 11;                               // D_INNER = 2048
    int l = t & (SEQ - 1);
    int b = t >> 10;                                 // SEQ = 1024

    float w0 = conv_w[d * 4 + 0], w1 = conv_w[d * 4 + 1];
    float w2 = conv_w[d * 4 + 2], w3 = conv_w[d * 4 + 3];

    const float* base = xz + (size_t)b * SEQ * (2 * D_INNER) + d;
    float acc = conv_b[d];
    if (l >= 3) acc += w0 * base[(size_t)(l - 3) * (2 * D_INNER)];
    if (l >= 2) acc += w1 * base[(size_t)(l - 2) * (2 * D_INNER)];
    if (l >= 1) acc += w2 * base[(size_t)(l - 1) * (2 * D_INNER)];
    acc += w3 * base[(size_t)l * (2 * D_INNER)];

    u[idx] = siluf(acc);
}

// ---------------------------------------------------------------------------
// Chunk-parallel selective scan.
// Group id g = (b*CHUNKS + c)*D_INNER + d; 16 lanes per group (one per state).
// Pass 1: per chunk, compute Aprod = prod(dA) and Hend = scan(h_in=0) end.
// Pass 2: combine chunk states sequentially -> Hin per chunk.
// Pass 3: replay chunk from Hin, fused C-projection + D-skip + silu(res) gate.
// ---------------------------------------------------------------------------
__global__ __launch_bounds__(256)
void scan_pass1(const float* __restrict__ delta, const float* __restrict__ u,
                const float* __restrict__ xdbl, const float* __restrict__ A_log,
                float* __restrict__ Aprod, float* __restrict__ Hend)
{
    int gid = blockIdx.x * 256 + threadIdx.x;
    int n = gid & 15;
    int g = gid >> 4;
    if (g >= BATCH * CHUNKS * D_INNER) return;
    int d  = g & (D_INNER - 1);
    int bc = g >> 11;
    int c  = bc & (CHUNKS - 1);
    int b  = bc >> 4;                       // CHUNKS = 16

    float An = -__expf(A_log[d * D_STATE + n]);
    const float* dp = delta + ((size_t)b * SEQ + c * LC) * D_INNER + d;
    const float* up = u     + ((size_t)b * SEQ + c * LC) * D_INNER + d;
    const float* xb = xdbl  + ((size_t)b * SEQ + c * LC) * 96;

    float h = 0.f, ap = 1.f;
    for (int l = 0; l < LC; ++l) {
        float dt = dp[(size_t)l * D_INNER];
        float ut = up[(size_t)l * D_INNER];
        float Bn = xb[l * 96 + DT_RANK + n];
        float da = __expf(dt * An);
        h  = da * h + dt * Bn * ut;
        ap *= da;
    }
    Aprod[gid] = ap;
    Hend[gid]  = h;
}

__global__ __launch_bounds__(256)
void scan_pass2(const float* __restrict__ Aprod, float* __restrict__ HendHin)
{
    int idx = blockIdx.x * 256 + threadIdx.x;      // (b*D + d)*16 + n
    if (idx >= BATCH * D_INNER * D_STATE) return;
    int n = idx & 15;
    int d = (idx >> 4) & (D_INNER - 1);
    int b = idx >> 15;

    float h = 0.f;
    for (int c = 0; c < CHUNKS; ++c) {
        size_t j = ((((size_t)b * CHUNKS + c) * D_INNER) + d) * 16 + n;
        float ap = Aprod[j];
        float he = HendHin[j];
        HendHin[j] = h;            // overwrite Hend with Hin (read-before-write)
        h = ap * h + he;
    }
}

__global__ __launch_bounds__(256)
void scan_pass3(const float* delta, const float* __restrict__ u,
                const float* __restrict__ xdbl, const float* __restrict__ xz,
                const float* __restrict__ A_log, const float* __restrict__ D_skip,
                const float* __restrict__ Hin, float* yg)
{
    int gid = blockIdx.x * 256 + threadIdx.x;
    int n = gid & 15;
    int g = gid >> 4;
    if (g >= BATCH * CHUNKS * D_INNER) return;
    int d  = g & (D_INNER - 1);
    int bc = g >> 11;
    int c  = bc & (CHUNKS - 1);
    int b  = bc >> 4;

    float An = -__expf(A_log[d * D_STATE + n]);
    float Dd = D_skip[d];
    float h  = Hin[gid];

    const float* dp = delta + ((size_t)b * SEQ + c * LC) * D_INNER + d;
    const float* up = u     + ((size_t)b * SEQ + c * LC) * D_INNER + d;
    const float* xb = xdbl  + ((size_t)b * SEQ + c * LC) * 96;
    const float* rp = xz    + ((size_t)b * SEQ + c * LC) * (2 * D_INNER) + D_INNER + d;
    float*       yp = yg    + ((size_t)b * SEQ + c * LC) * D_INNER + d;

    for (int l = 0; l < LC; ++l) {
        float dt = dp[(size_t)l * D_INNER];
        float ut = up[(size_t)l * D_INNER];
        float Bn = xb[l * 96 + DT_RANK + n];
        float Cn = xb[l * 96 + DT_RANK + D_STATE + n];

        h = __expf(dt * An) * h + dt * Bn * ut;
        float p = h * Cn;
        p += __shfl_xor(p, 1, 16);
        p += __shfl_xor(p, 2, 16);
        p += __shfl_xor(p, 4, 16);
        p += __shfl_xor(p, 8, 16);

        if (n == 0) {
            float res = rp[(size_t)l * (2 * D_INNER)];
            yp[(size_t)l * D_INNER] = (p + ut * Dd) * siluf(res);
        }
    }
}

// ---------------------------------------------------------------------------
extern "C" void kernel_launch(void* const* d_in, const int* in_sizes, int n_in,
                              void* d_out, int out_size, void* d_ws, size_t ws_size,
                              hipStream_t stream)
{
    const float* H      = (const float*)d_in[0];  // [B,L,1024]
    const float* Win    = (const float*)d_in[1];  // [1024, 4096]
    const float* convw  = (const float*)d_in[2];  // [2048,1,4]
    const float* convb  = (const float*)d_in[3];  // [2048]
    const float* xprojw = (const float*)d_in[4];  // [2048, 96]
    const float* dtw    = (const float*)d_in[5];  // [64, 2048]
    const float* dtb    = (const float*)d_in[6];  // [2048]
    const float* Alog   = (const float*)d_in[7];  // [2048, 16]
    const float* Dskip  = (const float*)d_in[8];  // [2048]
    const float* Wout   = (const float*)d_in[9];  // [2048, 1024]
    float* out = (float*)d_out;

    float* ws    = (float*)d_ws;
    float* xz    = ws;                                   // [NTOK, 4096]  32 MB
    float* u     = xz   + (size_t)NTOK * 4096;           // [NTOK, 2048]  16 MB
    float* xdbl  = u    + (size_t)NTOK * 2048;           // [NTOK, 96]    0.75 MB
    float* delta = xdbl + (size_t)NTOK * 96;             // [NTOK, 2048]  16 MB
    float* yg    = delta;                                // in-place over delta
    float* Aprod = delta + (size_t)NTOK * 2048;          // [B*CHUNKS*D*16] 4 MB
    float* Hend  = Aprod + (size_t)BATCH * CHUNKS * D_INNER * 16;  // 4 MB (becomes Hin)

    dim3 blk(256);

    // 1) xz = H @ Win   [2048 x 4096 x 1024]
    gemm_f32<false, false><<<dim3(4096 / 64, NTOK / 64), blk, 0, stream>>>(
        H, Win, nullptr, xz, NTOK, 2 * D_INNER, D_MODEL, D_MODEL, 2 * D_INNER, 2 * D_INNER);

    // 2) u = silu(causal_depthwise_conv(x) + b)
    conv_silu<<<(NTOK * D_INNER) / 256, blk, 0, stream>>>(xz, convw, convb, u);

    // 3) x_dbl = u @ x_proj_w   [2048 x 96 x 2048]
    gemm_f32<false, false><<<dim3(2, NTOK / 64), blk, 0, stream>>>(
        u, xprojw, nullptr, xdbl, NTOK, 96, D_INNER, D_INNER, 96, 96);

    // 4) delta = softplus(x_dbl[:, :64] @ dt_proj_w + dt_proj_b)  [2048 x 2048 x 64]
    gemm_f32<true, true><<<dim3(D_INNER / 64, NTOK / 64), blk, 0, stream>>>(
        xdbl, dtw, dtb, delta, NTOK, D_INNER, DT_RANK, 96, D_INNER, D_INNER);

    // 5) chunk-parallel selective scan (+ D-skip + silu(res) gate fused in pass 3)
    {
        int nthr = BATCH * CHUNKS * D_INNER * 16;        // 1,048,576
        scan_pass1<<<nthr / 256, blk, 0, stream>>>(delta, u, xdbl, Alog, Aprod, Hend);
        scan_pass2<<<(BATCH * D_INNER * 16) / 256, blk, 0, stream>>>(Aprod, Hend);
        scan_pass3<<<nthr / 256, blk, 0, stream>>>(delta, u, xdbl, xz, Alog, Dskip,
                                                   Hend /*now Hin*/, yg);
    }

    // 6) out = yg @ Wout   [2048 x 1024 x 2048]
    gemm_f32<false, false><<<dim3(D_MODEL / 64, NTOK / 64), blk, 0, stream>>>(
        yg, Wout, nullptr, out, NTOK, D_MODEL, D_INNER, D_INNER, D_MODEL, D_MODEL);
}

// Round 4
// 492.484 us; speedup vs baseline: 2.7405x; 1.5568x over previous
//
#include <hip/hip_runtime.h>
#include <hip/hip_bf16.h>
#include <cstdint>

#define D_MODEL  1024
#define D_INNER  2048
#define D_STATE  16
#define DT_RANK  64
#define KERW     4
#define BATCH    2
#define SEQ      1024
#define NTOK     (BATCH * SEQ)
#define CHUNKS   16
#define LC       (SEQ / CHUNKS)     // 64 steps per chunk

typedef _Float16 h8 __attribute__((ext_vector_type(8)));
typedef _Float16 h4 __attribute__((ext_vector_type(4)));
typedef float    f32x4 __attribute__((ext_vector_type(4)));

__device__ __forceinline__ float siluf(float x) {
    return x / (1.f + __expf(-x));
}

#define GLOAD_LDS16(g, p) __builtin_amdgcn_global_load_lds( \
    (const __attribute__((address_space(1))) void*)(g),      \
    (__attribute__((address_space(3))) void*)(p), 16, 0, 0)

// ---------------------------------------------------------------------------
// fp32 -> fp16 elementwise (vectorized x4)
// ---------------------------------------------------------------------------
__global__ __launch_bounds__(256)
void f32_to_f16_k(const float* __restrict__ in, _Float16* __restrict__ out, int n4)
{
    int i = blockIdx.x * 256 + threadIdx.x;
    if (i >= n4) return;
    float4 v = ((const float4*)in)[i];
    h4 h = { (_Float16)v.x, (_Float16)v.y, (_Float16)v.z, (_Float16)v.w };
    *(h4*)(out + (size_t)i * 4) = h;
}

// ---------------------------------------------------------------------------
// Pack fp32 B[K][NN] row-major -> fp16 Bp[K/8][NN][8]  (fragment-order:
// 16B global chunk = 8 consecutive k for one n). Grid covers (K/8)*NN exactly.
// ---------------------------------------------------------------------------
template<int NN>
__global__ __launch_bounds__(256)
void pack_b_f16(const float* __restrict__ B, _Float16* __restrict__ Bp, int K)
{
    constexpr int SH = (NN == 4096) ? 12 : 10;
    int gid = blockIdx.x * 256 + threadIdx.x;
    int n  = gid & (NN - 1);
    int kb = gid >> SH;
    h8 v;
    #pragma unroll
    for (int j = 0; j < 8; ++j)
        v[j] = (_Float16)B[(size_t)(kb * 8 + j) * NN + n];
    *(h8*)(Bp + (size_t)gid * 8) = v;
}

// ---------------------------------------------------------------------------
// fp16 MFMA GEMM: C[M,N] = A[M,K] @ B[K,N], fp32 out.
// A: fp16 row-major (lda in elements); Bp: fp16 packed [K/8][N][8].
// 128x128 tile, BK=32, 256 threads = 4 waves (2x2), mfma_f32_16x16x32_f16.
// M, N, K all multiples of 128/128/32. global_load_lds width-16 staging.
// LDS layout [kg][row][8] -> quarter-wave ds_read_b128 spans all 32 banks.
// ---------------------------------------------------------------------------
__global__ __launch_bounds__(256)
void gemm_f16_mfma(const _Float16* __restrict__ A, const _Float16* __restrict__ Bp,
                   float* __restrict__ C, int N, int K, int lda, int ldc)
{
    __shared__ alignas(16) _Float16 As[4 * 128 * 8];   // 8 KB
    __shared__ alignas(16) _Float16 Bs[4 * 128 * 8];   // 8 KB

    const int tid = threadIdx.x;
    const int l = tid & 63, w = tid >> 6;
    const int wm = w >> 1, wn = w & 1;          // 2x2 wave grid, 64x64 each
    const int bm = blockIdx.y * 128, bn = blockIdx.x * 128;

    f32x4 acc[4][4] = {};

    const int kg = l >> 4, r = l & 15;

    for (int k0 = 0; k0 < K; k0 += 32) {
        // ---- stage A tile: chunks c = (kgc*128 + row); 512 chunks of 16B
        #pragma unroll
        for (int i = 0; i < 2; ++i) {
            int c = i * 256 + w * 64 + l;
            int row = c & 127, kgc = c >> 7;
            const _Float16* g = A + (size_t)(bm + row) * lda + k0 + kgc * 8;
            GLOAD_LDS16(g, As + (size_t)(i * 256 + w * 64) * 8);
        }
        // ---- stage B tile: chunks c = (kgc*128 + col)
        #pragma unroll
        for (int i = 0; i < 2; ++i) {
            int c = i * 256 + w * 64 + l;
            int col = c & 127, kgc = c >> 7;
            const _Float16* g = Bp + ((size_t)((k0 >> 3) + kgc) * N + bn + col) * 8;
            GLOAD_LDS16(g, Bs + (size_t)(i * 256 + w * 64) * 8);
        }
        __syncthreads();

        h8 a[4], b[4];
        #pragma unroll
        for (int mi = 0; mi < 4; ++mi)
            a[mi] = *(const h8*)(As + (size_t)(kg * 128 + wm * 64 + mi * 16 + r) * 8);
        #pragma unroll
        for (int ni = 0; ni < 4; ++ni)
            b[ni] = *(const h8*)(Bs + (size_t)(kg * 128 + wn * 64 + ni * 16 + r) * 8);

        #pragma unroll
        for (int mi = 0; mi < 4; ++mi)
            #pragma unroll
            for (int ni = 0; ni < 4; ++ni)
                acc[mi][ni] = __builtin_amdgcn_mfma_f32_16x16x32_f16(
                    a[mi], b[ni], acc[mi][ni], 0, 0, 0);

        __syncthreads();
    }

    // epilogue: C/D layout col = lane&15, row = (lane>>4)*4 + reg  [m89-verified]
    const int q = l >> 4;
    #pragma unroll
    for (int mi = 0; mi < 4; ++mi)
        #pragma unroll
        for (int ni = 0; ni < 4; ++ni)
            #pragma unroll
            for (int j = 0; j < 4; ++j)
                C[(size_t)(bm + wm * 64 + mi * 16 + q * 4 + j) * ldc
                  + (bn + wn * 64 + ni * 16 + r)] = acc[mi][ni][j];
}

// ---------------------------------------------------------------------------
// Generic fp32 GEMM (kept for the two small GEMMs): 64x64 tile.
// ---------------------------------------------------------------------------
template<bool BIAS, bool SOFTPLUS>
__global__ __launch_bounds__(256)
void gemm_f32(const float* __restrict__ A, const float* __restrict__ B,
              const float* __restrict__ bias, float* __restrict__ C,
              int M, int N, int K, int lda, int ldb, int ldc)
{
    __shared__ float As[16][68];   // [k][m]
    __shared__ float Bs[16][68];   // [k][n]
    const int tid = threadIdx.x;
    const int tx = tid & 15, ty = tid >> 4;
    const int bm = blockIdx.y * 64, bn = blockIdx.x * 64;

    float acc[4][4] = {};

    const int ar  = tid >> 2;
    const int ac4 = (tid & 3) << 2;
    const int bkr = tid >> 4;
    const int bc4 = (tid & 15) << 2;

    for (int k0 = 0; k0 < K; k0 += 16) {
        float4 av = make_float4(0.f, 0.f, 0.f, 0.f);
        {
            int row = bm + ar;
            if (row < M)
                av = *(const float4*)(A + (size_t)row * lda + (k0 + ac4));
        }
        As[ac4 + 0][ar] = av.x; As[ac4 + 1][ar] = av.y;
        As[ac4 + 2][ar] = av.z; As[ac4 + 3][ar] = av.w;

        float4 bv = make_float4(0.f, 0.f, 0.f, 0.f);
        {
            int col = bn + bc4;
            const float* bp = B + (size_t)(k0 + bkr) * ldb + col;
            if (col + 3 < N) {
                bv = *(const float4*)bp;
            } else {
                if (col + 0 < N) bv.x = bp[0];
                if (col + 1 < N) bv.y = bp[1];
                if (col + 2 < N) bv.z = bp[2];
                if (col + 3 < N) bv.w = bp[3];
            }
        }
        Bs[bkr][bc4 + 0] = bv.x; Bs[bkr][bc4 + 1] = bv.y;
        Bs[bkr][bc4 + 2] = bv.z; Bs[bkr][bc4 + 3] = bv.w;

        __syncthreads();

        #pragma unroll
        for (int kk = 0; kk < 16; ++kk) {
            float a[4], b[4];
            #pragma unroll
            for (int i = 0; i < 4; ++i) a[i] = As[kk][ty * 4 + i];
            #pragma unroll
            for (int j = 0; j < 4; ++j) b[j] = Bs[kk][tx * 4 + j];
            #pragma unroll
            for (int i = 0; i < 4; ++i)
                #pragma unroll
                for (int j = 0; j < 4; ++j)
                    acc[i][j] = fmaf(a[i], b[j], acc[i][j]);
        }
        __syncthreads();
    }

    #pragma unroll
    for (int i = 0; i < 4; ++i) {
        int row = bm + ty * 4 + i;
        if (row >= M) continue;
        #pragma unroll
        for (int j = 0; j < 4; ++j) {
            int col = bn + tx * 4 + j;
            if (col >= N) continue;
            float v = acc[i][j];
            if (BIAS) v += bias[col];
            if (SOFTPLUS) v = (v > 20.f) ? v : log1pf(__expf(v));
            C[(size_t)row * ldc + col] = v;
        }
    }
}

// ---------------------------------------------------------------------------
// Depthwise causal conv (K=4) + bias + SiLU.
// ---------------------------------------------------------------------------
__global__ __launch_bounds__(256)
void conv_silu(const float* __restrict__ xz, const float* __restrict__ conv_w,
               const float* __restrict__ conv_b, float* __restrict__ u)
{
    int idx = blockIdx.x * 256 + threadIdx.x;
    if (idx >= NTOK * D_INNER) return;
    int d = idx & (D_INNER - 1);
    int t = idx >> 11;
    int l = t & (SEQ - 1);
    int b = t >> 10;

    float w0 = conv_w[d * 4 + 0], w1 = conv_w[d * 4 + 1];
    float w2 = conv_w[d * 4 + 2], w3 = conv_w[d * 4 + 3];

    const float* base = xz + (size_t)b * SEQ * (2 * D_INNER) + d;
    float acc = conv_b[d];
    if (l >= 3) acc += w0 * base[(size_t)(l - 3) * (2 * D_INNER)];
    if (l >= 2) acc += w1 * base[(size_t)(l - 2) * (2 * D_INNER)];
    if (l >= 1) acc += w2 * base[(size_t)(l - 1) * (2 * D_INNER)];
    acc += w3 * base[(size_t)l * (2 * D_INNER)];

    u[idx] = siluf(acc);
}

// ---------------------------------------------------------------------------
// Chunk-parallel selective scan (3 passes).
// ---------------------------------------------------------------------------
__global__ __launch_bounds__(256)
void scan_pass1(const float* __restrict__ delta, const float* __restrict__ u,
                const float* __restrict__ xdbl, const float* __restrict__ A_log,
                float* __restrict__ Aprod, float* __restrict__ Hend)
{
    int gid = blockIdx.x * 256 + threadIdx.x;
    int n = gid & 15;
    int g = gid >> 4;
    if (g >= BATCH * CHUNKS * D_INNER) return;
    int d  = g & (D_INNER - 1);
    int bc = g >> 11;
    int c  = bc & (CHUNKS - 1);
    int b  = bc >> 4;

    float An = -__expf(A_log[d * D_STATE + n]);
    const float* dp = delta + ((size_t)b * SEQ + c * LC) * D_INNER + d;
    const float* up = u     + ((size_t)b * SEQ + c * LC) * D_INNER + d;
    const float* xb = xdbl  + ((size_t)b * SEQ + c * LC) * 96;

    float h = 0.f, ap = 1.f;
    for (int l = 0; l < LC; ++l) {
        float dt = dp[(size_t)l * D_INNER];
        float ut = up[(size_t)l * D_INNER];
        float Bn = xb[l * 96 + DT_RANK + n];
        float da = __expf(dt * An);
        h  = da * h + dt * Bn * ut;
        ap *= da;
    }
    Aprod[gid] = ap;
    Hend[gid]  = h;
}

__global__ __launch_bounds__(256)
void scan_pass2(const float* __restrict__ Aprod, float* __restrict__ HendHin)
{
    int idx = blockIdx.x * 256 + threadIdx.x;
    if (idx >= BATCH * D_INNER * D_STATE) return;
    int n = idx & 15;
    int d = (idx >> 4) & (D_INNER - 1);
    int b = idx >> 15;

    float h = 0.f;
    for (int c = 0; c < CHUNKS; ++c) {
        size_t j = ((((size_t)b * CHUNKS + c) * D_INNER) + d) * 16 + n;
        float ap = Aprod[j];
        float he = HendHin[j];
        HendHin[j] = h;            // Hend -> Hin in place (read-before-write)
        h = ap * h + he;
    }
}

// pass 3: replay + C-proj + D-skip + silu(res) gate; writes fp16 yg with
// row stride 8192 halfs (lives in the dead x-half of the xz buffer).
__global__ __launch_bounds__(256)
void scan_pass3(const float* __restrict__ delta, const float* __restrict__ u,
                const float* __restrict__ xdbl, const float* __restrict__ xz,
                const float* __restrict__ A_log, const float* __restrict__ D_skip,
                const float* __restrict__ Hin, _Float16* __restrict__ ygh)
{
    int gid = blockIdx.x * 256 + threadIdx.x;
    int n = gid & 15;
    int g = gid >> 4;
    if (g >= BATCH * CHUNKS * D_INNER) return;
    int d  = g & (D_INNER - 1);
    int bc = g >> 11;
    int c  = bc & (CHUNKS - 1);
    int b  = bc >> 4;

    float An = -__expf(A_log[d * D_STATE + n]);
    float Dd = D_skip[d];
    float h  = Hin[gid];

    const float* dp = delta + ((size_t)b * SEQ + c * LC) * D_INNER + d;
    const float* up = u     + ((size_t)b * SEQ + c * LC) * D_INNER + d;
    const float* xb = xdbl  + ((size_t)b * SEQ + c * LC) * 96;
    const float* rp = xz    + ((size_t)b * SEQ + c * LC) * (2 * D_INNER) + D_INNER + d;
    _Float16*    yp = ygh   + ((size_t)b * SEQ + c * LC) * 8192 + d;

    for (int l = 0; l < LC; ++l) {
        float dt = dp[(size_t)l * D_INNER];
        float ut = up[(size_t)l * D_INNER];
        float Bn = xb[l * 96 + DT_RANK + n];
        float Cn = xb[l * 96 + DT_RANK + D_STATE + n];

        h = __expf(dt * An) * h + dt * Bn * ut;
        float p = h * Cn;
        p += __shfl_xor(p, 1, 16);
        p += __shfl_xor(p, 2, 16);
        p += __shfl_xor(p, 4, 16);
        p += __shfl_xor(p, 8, 16);

        if (n == 0) {
            float res = rp[(size_t)l * (2 * D_INNER)];
            yp[(size_t)l * 8192] = (_Float16)((p + ut * Dd) * siluf(res));
        }
    }
}

// ---------------------------------------------------------------------------
extern "C" void kernel_launch(void* const* d_in, const int* in_sizes, int n_in,
                              void* d_out, int out_size, void* d_ws, size_t ws_size,
                              hipStream_t stream)
{
    const float* H      = (const float*)d_in[0];  // [B,L,1024]
    const float* Win    = (const float*)d_in[1];  // [1024, 4096]
    const float* convw  = (const float*)d_in[2];  // [2048,1,4]
    const float* convb  = (const float*)d_in[3];  // [2048]
    const float* xprojw = (const float*)d_in[4];  // [2048, 96]
    const float* dtw    = (const float*)d_in[5];  // [64, 2048]
    const float* dtb    = (const float*)d_in[6];  // [2048]
    const float* Alog   = (const float*)d_in[7];  // [2048, 16]
    const float* Dskip  = (const float*)d_in[8];  // [2048]
    const float* Wout   = (const float*)d_in[9];  // [2048, 1024]
    float* out = (float*)d_out;

    float* ws    = (float*)d_ws;
    float* xz    = ws;                                   // [NTOK,4096] 32MB
    float* u     = xz   + (size_t)NTOK * 4096;           // 16MB
    float* xdbl  = u    + (size_t)NTOK * 2048;           // 0.75MB
    float* delta = xdbl + (size_t)NTOK * 96;             // 16MB
    float* Aprod = delta + (size_t)NTOK * 2048;          // 4MB
    float* Hend  = Aprod + (size_t)BATCH * CHUNKS * D_INNER * 16;  // 4MB

    // fp16 aliases (lifetime-disjoint with their hosts):
    _Float16* Hh    = (_Float16*)delta;                  // 4MB, dead once GEMM3 writes delta
    _Float16* Winp  = (_Float16*)delta + 2 * 1024 * 1024;// 8MB, same lifetime
    _Float16* ygh   = (_Float16*)xz;                     // stride 8192; uses dead x-half bytes
    _Float16* Woutp = (_Float16*)Aprod;                  // 4MB, Aprod dead after pass2

    dim3 blk(256);

    // 0a) Hh = fp16(H)
    f32_to_f16_k<<<(NTOK * D_MODEL / 4) / 256, blk, 0, stream>>>(H, Hh, NTOK * D_MODEL / 4);
    // 0b) Winp = pack(fp16(Win))  [1024 x 4096]
    pack_b_f16<4096><<<((D_MODEL / 8) * 4096) / 256, blk, 0, stream>>>(Win, Winp, D_MODEL);

    // 1) xz = H @ Win   (MFMA fp16)
    gemm_f16_mfma<<<dim3(4096 / 128, NTOK / 128), blk, 0, stream>>>(
        Hh, Winp, xz, 2 * D_INNER, D_MODEL, D_MODEL, 2 * D_INNER);

    // 2) u = silu(depthwise_conv(x) + b)
    conv_silu<<<(NTOK * D_INNER) / 256, blk, 0, stream>>>(xz, convw, convb, u);

    // 3) x_dbl = u @ x_proj_w   (fp32, N=96)
    gemm_f32<false, false><<<dim3(2, NTOK / 64), blk, 0, stream>>>(
        u, xprojw, nullptr, xdbl, NTOK, 96, D_INNER, D_INNER, 96, 96);

    // 4) delta = softplus(x_dbl[:, :64] @ dt_proj_w + dt_proj_b)  (fp32, K=64)
    gemm_f32<true, true><<<dim3(D_INNER / 64, NTOK / 64), blk, 0, stream>>>(
        xdbl, dtw, dtb, delta, NTOK, D_INNER, DT_RANK, 96, D_INNER, D_INNER);

    // 5) chunk-parallel scan
    {
        int nthr = BATCH * CHUNKS * D_INNER * 16;
        scan_pass1<<<nthr / 256, blk, 0, stream>>>(delta, u, xdbl, Alog, Aprod, Hend);
        scan_pass2<<<(BATCH * D_INNER * 16) / 256, blk, 0, stream>>>(Aprod, Hend);
        scan_pass3<<<nthr / 256, blk, 0, stream>>>(delta, u, xdbl, xz, Alog, Dskip,
                                                   Hend /*Hin*/, ygh);
    }

    // 5b) Woutp = pack(fp16(Wout))  [2048 x 1024]  (Aprod dead now)
    pack_b_f16<1024><<<((D_INNER / 8) * 1024) / 256, blk, 0, stream>>>(Wout, Woutp, D_INNER);

    // 6) out = yg @ Wout   (MFMA fp16; A stride 8192)
    gemm_f16_mfma<<<dim3(1024 / 128, NTOK / 128), blk, 0, stream>>>(
        ygh, Woutp, out, D_MODEL, D_INNER, 8192, D_MODEL);
}

// Round 6
// 392.789 us; speedup vs baseline: 3.4360x; 1.2538x over previous
//
#include <hip/hip_runtime.h>
#include <hip/hip_bf16.h>
#include <cstdint>

#define D_MODEL  1024
#define D_INNER  2048
#define D_STATE  16
#define DT_RANK  64
#define KERW     4
#define BATCH    2
#define SEQ      1024
#define NTOK     (BATCH * SEQ)
#define CHUNKS   16
#define LC       (SEQ / CHUNKS)     // 64 steps per chunk

typedef _Float16 h8 __attribute__((ext_vector_type(8)));
typedef _Float16 h4 __attribute__((ext_vector_type(4)));
typedef float    f32x4 __attribute__((ext_vector_type(4)));

__device__ __forceinline__ float siluf(float x) {
    return x / (1.f + __expf(-x));
}

#define GLOAD_LDS16(g, p) __builtin_amdgcn_global_load_lds( \
    (const __attribute__((address_space(1))) void*)(g),      \
    (__attribute__((address_space(3))) void*)(p), 16, 0, 0)

// ---------------------------------------------------------------------------
// fp32 -> fp16 elementwise (vectorized x4)
// ---------------------------------------------------------------------------
__global__ __launch_bounds__(256)
void f32_to_f16_k(const float* __restrict__ in, _Float16* __restrict__ out, int n4)
{
    int i = blockIdx.x * 256 + threadIdx.x;
    if (i >= n4) return;
    float4 v = ((const float4*)in)[i];
    h4 h = { (_Float16)v.x, (_Float16)v.y, (_Float16)v.z, (_Float16)v.w };
    *(h4*)(out + (size_t)i * 4) = h;
}

// ---------------------------------------------------------------------------
// Pack fp32 B[K][NN] row-major -> fp16 Bp[K/8][NN][8]
// ---------------------------------------------------------------------------
template<int NN>
__global__ __launch_bounds__(256)
void pack_b_f16(const float* __restrict__ B, _Float16* __restrict__ Bp, int K)
{
    constexpr int SH = (NN == 4096) ? 12 : 10;
    int gid = blockIdx.x * 256 + threadIdx.x;
    int n  = gid & (NN - 1);
    int kb = gid >> SH;
    h8 v;
    #pragma unroll
    for (int j = 0; j < 8; ++j)
        v[j] = (_Float16)B[(size_t)(kb * 8 + j) * NN + n];
    *(h8*)(Bp + (size_t)gid * 8) = v;
}

// ---------------------------------------------------------------------------
// fp16 MFMA GEMM: C[M,N] = A[M,K] @ B[K,N], fp32 out.
// 128x128 tile, BK=32, 4 waves (2x2), mfma_f32_16x16x32_f16.
// ---------------------------------------------------------------------------
__global__ __launch_bounds__(256)
void gemm_f16_mfma(const _Float16* __restrict__ A, const _Float16* __restrict__ Bp,
                   float* __restrict__ C, int N, int K, int lda, int ldc)
{
    __shared__ alignas(16) _Float16 As[4 * 128 * 8];   // 8 KB
    __shared__ alignas(16) _Float16 Bs[4 * 128 * 8];   // 8 KB

    const int tid = threadIdx.x;
    const int l = tid & 63, w = tid >> 6;
    const int wm = w >> 1, wn = w & 1;
    const int bm = blockIdx.y * 128, bn = blockIdx.x * 128;

    f32x4 acc[4][4] = {};

    const int kg = l >> 4, r = l & 15;

    for (int k0 = 0; k0 < K; k0 += 32) {
        #pragma unroll
        for (int i = 0; i < 2; ++i) {
            int c = i * 256 + w * 64 + l;
            int row = c & 127, kgc = c >> 7;
            const _Float16* g = A + (size_t)(bm + row) * lda + k0 + kgc * 8;
            GLOAD_LDS16(g, As + (size_t)(i * 256 + w * 64) * 8);
        }
        #pragma unroll
        for (int i = 0; i < 2; ++i) {
            int c = i * 256 + w * 64 + l;
            int col = c & 127, kgc = c >> 7;
            const _Float16* g = Bp + ((size_t)((k0 >> 3) + kgc) * N + bn + col) * 8;
            GLOAD_LDS16(g, Bs + (size_t)(i * 256 + w * 64) * 8);
        }
        __syncthreads();

        h8 a[4], b[4];
        #pragma unroll
        for (int mi = 0; mi < 4; ++mi)
            a[mi] = *(const h8*)(As + (size_t)(kg * 128 + wm * 64 + mi * 16 + r) * 8);
        #pragma unroll
        for (int ni = 0; ni < 4; ++ni)
            b[ni] = *(const h8*)(Bs + (size_t)(kg * 128 + wn * 64 + ni * 16 + r) * 8);

        #pragma unroll
        for (int mi = 0; mi < 4; ++mi)
            #pragma unroll
            for (int ni = 0; ni < 4; ++ni)
                acc[mi][ni] = __builtin_amdgcn_mfma_f32_16x16x32_f16(
                    a[mi], b[ni], acc[mi][ni], 0, 0, 0);

        __syncthreads();
    }

    const int q = l >> 4;
    #pragma unroll
    for (int mi = 0; mi < 4; ++mi)
        #pragma unroll
        for (int ni = 0; ni < 4; ++ni)
            #pragma unroll
            for (int j = 0; j < 4; ++j)
                C[(size_t)(bm + wm * 64 + mi * 16 + q * 4 + j) * ldc
                  + (bn + wn * 64 + ni * 16 + r)] = acc[mi][ni][j];
}

// ---------------------------------------------------------------------------
// Generic fp32 GEMM (used for GEMM3 only now): 64x64 tile.
// ---------------------------------------------------------------------------
template<bool BIAS, bool SOFTPLUS>
__global__ __launch_bounds__(256)
void gemm_f32(const float* __restrict__ A, const float* __restrict__ B,
              const float* __restrict__ bias, float* __restrict__ C,
              int M, int N, int K, int lda, int ldb, int ldc)
{
    __shared__ float As[16][68];
    __shared__ float Bs[16][68];
    const int tid = threadIdx.x;
    const int tx = tid & 15, ty = tid >> 4;
    const int bm = blockIdx.y * 64, bn = blockIdx.x * 64;

    float acc[4][4] = {};

    const int ar  = tid >> 2;
    const int ac4 = (tid & 3) << 2;
    const int bkr = tid >> 4;
    const int bc4 = (tid & 15) << 2;

    for (int k0 = 0; k0 < K; k0 += 16) {
        float4 av = make_float4(0.f, 0.f, 0.f, 0.f);
        {
            int row = bm + ar;
            if (row < M)
                av = *(const float4*)(A + (size_t)row * lda + (k0 + ac4));
        }
        As[ac4 + 0][ar] = av.x; As[ac4 + 1][ar] = av.y;
        As[ac4 + 2][ar] = av.z; As[ac4 + 3][ar] = av.w;

        float4 bv = make_float4(0.f, 0.f, 0.f, 0.f);
        {
            int col = bn + bc4;
            const float* bp = B + (size_t)(k0 + bkr) * ldb + col;
            if (col + 3 < N) {
                bv = *(const float4*)bp;
            } else {
                if (col + 0 < N) bv.x = bp[0];
                if (col + 1 < N) bv.y = bp[1];
                if (col + 2 < N) bv.z = bp[2];
                if (col + 3 < N) bv.w = bp[3];
            }
        }
        Bs[bkr][bc4 + 0] = bv.x; Bs[bkr][bc4 + 1] = bv.y;
        Bs[bkr][bc4 + 2] = bv.z; Bs[bkr][bc4 + 3] = bv.w;

        __syncthreads();

        #pragma unroll
        for (int kk = 0; kk < 16; ++kk) {
            float a[4], b[4];
            #pragma unroll
            for (int i = 0; i < 4; ++i) a[i] = As[kk][ty * 4 + i];
            #pragma unroll
            for (int j = 0; j < 4; ++j) b[j] = Bs[kk][tx * 4 + j];
            #pragma unroll
            for (int i = 0; i < 4; ++i)
                #pragma unroll
                for (int j = 0; j < 4; ++j)
                    acc[i][j] = fmaf(a[i], b[j], acc[i][j]);
        }
        __syncthreads();
    }

    #pragma unroll
    for (int i = 0; i < 4; ++i) {
        int row = bm + ty * 4 + i;
        if (row >= M) continue;
        #pragma unroll
        for (int j = 0; j < 4; ++j) {
            int col = bn + tx * 4 + j;
            if (col >= N) continue;
            float v = acc[i][j];
            if (BIAS) v += bias[col];
            if (SOFTPLUS) v = (v > 20.f) ? v : log1pf(__expf(v));
            C[(size_t)row * ldc + col] = v;
        }
    }
}

// ---------------------------------------------------------------------------
// Split-K fp32 GEMM for GEMM2 (M=2048, N=96, K=2048):
// grid (ceil(N/64), M/64, SPLIT). Each z-slice does K/SPLIT and writes
// partials at part + z*M*ldc.
// ---------------------------------------------------------------------------
__global__ __launch_bounds__(256)
void gemm_f32_splitk(const float* __restrict__ A, const float* __restrict__ B,
                     float* __restrict__ part,
                     int M, int N, int K, int lda, int ldb, int ldc)
{
    __shared__ float As[16][68];
    __shared__ float Bs[16][68];
    const int tid = threadIdx.x;
    const int tx = tid & 15, ty = tid >> 4;
    const int bm = blockIdx.y * 64, bn = blockIdx.x * 64;
    const int kslice = K / gridDim.z;
    const int kbeg = blockIdx.z * kslice;

    float acc[4][4] = {};

    const int ar  = tid >> 2;
    const int ac4 = (tid & 3) << 2;
    const int bkr = tid >> 4;
    const int bc4 = (tid & 15) << 2;

    for (int k0 = kbeg; k0 < kbeg + kslice; k0 += 16) {
        float4 av;
        {
            int row = bm + ar;
            av = *(const float4*)(A + (size_t)row * lda + (k0 + ac4));
        }
        As[ac4 + 0][ar] = av.x; As[ac4 + 1][ar] = av.y;
        As[ac4 + 2][ar] = av.z; As[ac4 + 3][ar] = av.w;

        float4 bv = make_float4(0.f, 0.f, 0.f, 0.f);
        {
            int col = bn + bc4;
            const float* bp = B + (size_t)(k0 + bkr) * ldb + col;
            if (col + 3 < N) {
                bv = *(const float4*)bp;
            } else {
                if (col + 0 < N) bv.x = bp[0];
                if (col + 1 < N) bv.y = bp[1];
                if (col + 2 < N) bv.z = bp[2];
                if (col + 3 < N) bv.w = bp[3];
            }
        }
        Bs[bkr][bc4 + 0] = bv.x; Bs[bkr][bc4 + 1] = bv.y;
        Bs[bkr][bc4 + 2] = bv.z; Bs[bkr][bc4 + 3] = bv.w;

        __syncthreads();

        #pragma unroll
        for (int kk = 0; kk < 16; ++kk) {
            float a[4], b[4];
            #pragma unroll
            for (int i = 0; i < 4; ++i) a[i] = As[kk][ty * 4 + i];
            #pragma unroll
            for (int j = 0; j < 4; ++j) b[j] = Bs[kk][tx * 4 + j];
            #pragma unroll
            for (int i = 0; i < 4; ++i)
                #pragma unroll
                for (int j = 0; j < 4; ++j)
                    acc[i][j] = fmaf(a[i], b[j], acc[i][j]);
        }
        __syncthreads();
    }

    float* dst = part + (size_t)blockIdx.z * M * ldc;
    #pragma unroll
    for (int i = 0; i < 4; ++i) {
        int row = bm + ty * 4 + i;
        #pragma unroll
        for (int j = 0; j < 4; ++j) {
            int col = bn + tx * 4 + j;
            if (col >= N) continue;
            dst[(size_t)row * ldc + col] = acc[i][j];
        }
    }
}

__global__ __launch_bounds__(256)
void reduce_splitk(const float* __restrict__ part, float* __restrict__ out,
                   int n, int S)
{
    int i = blockIdx.x * 256 + threadIdx.x;
    if (i >= n) return;
    float s = 0.f;
    for (int j = 0; j < S; ++j) s += part[(size_t)j * n + i];
    out[i] = s;
}

// ---------------------------------------------------------------------------
// Depthwise causal conv (K=4) + bias + SiLU.
// ---------------------------------------------------------------------------
__global__ __launch_bounds__(256)
void conv_silu(const float* __restrict__ xz, const float* __restrict__ conv_w,
               const float* __restrict__ conv_b, float* __restrict__ u)
{
    int idx = blockIdx.x * 256 + threadIdx.x;
    if (idx >= NTOK * D_INNER) return;
    int d = idx & (D_INNER - 1);
    int t = idx >> 11;
    int l = t & (SEQ - 1);
    int b = t >> 10;

    float w0 = conv_w[d * 4 + 0], w1 = conv_w[d * 4 + 1];
    float w2 = conv_w[d * 4 + 2], w3 = conv_w[d * 4 + 3];

    const float* base = xz + (size_t)b * SEQ * (2 * D_INNER) + d;
    float acc = conv_b[d];
    if (l >= 3) acc += w0 * base[(size_t)(l - 3) * (2 * D_INNER)];
    if (l >= 2) acc += w1 * base[(size_t)(l - 2) * (2 * D_INNER)];
    if (l >= 1) acc += w2 * base[(size_t)(l - 1) * (2 * D_INNER)];
    acc += w3 * base[(size_t)l * (2 * D_INNER)];

    u[idx] = siluf(acc);
}

// ---------------------------------------------------------------------------
// Chunk-parallel selective scan (3 passes).
// ---------------------------------------------------------------------------
__global__ __launch_bounds__(256)
void scan_pass1(const float* __restrict__ delta, const float* __restrict__ u,
                const float* __restrict__ xdbl, const float* __restrict__ A_log,
                float* __restrict__ Aprod, float* __restrict__ Hend)
{
    int gid = blockIdx.x * 256 + threadIdx.x;
    int n = gid & 15;
    int g = gid >> 4;
    if (g >= BATCH * CHUNKS * D_INNER) return;
    int d  = g & (D_INNER - 1);
    int bc = g >> 11;
    int c  = bc & (CHUNKS - 1);
    int b  = bc >> 4;

    float An = -__expf(A_log[d * D_STATE + n]);
    const float* dp = delta + ((size_t)b * SEQ + c * LC) * D_INNER + d;
    const float* up = u     + ((size_t)b * SEQ + c * LC) * D_INNER + d;
    const float* xb = xdbl  + ((size_t)b * SEQ + c * LC) * 96;

    float h = 0.f, ap = 1.f;
    for (int l = 0; l < LC; ++l) {
        float dt = dp[(size_t)l * D_INNER];
        float ut = up[(size_t)l * D_INNER];
        float Bn = xb[l * 96 + DT_RANK + n];
        float da = __expf(dt * An);
        h  = da * h + dt * Bn * ut;
        ap *= da;
    }
    Aprod[gid] = ap;
    Hend[gid]  = h;
}

__global__ __launch_bounds__(256)
void scan_pass2(const float* __restrict__ Aprod, float* __restrict__ HendHin)
{
    int idx = blockIdx.x * 256 + threadIdx.x;
    if (idx >= BATCH * D_INNER * D_STATE) return;
    int n = idx & 15;
    int d = (idx >> 4) & (D_INNER - 1);
    int b = idx >> 15;

    float h = 0.f;
    for (int c = 0; c < CHUNKS; ++c) {
        size_t j = ((((size_t)b * CHUNKS + c) * D_INNER) + d) * 16 + n;
        float ap = Aprod[j];
        float he = HendHin[j];
        HendHin[j] = h;
        h = ap * h + he;
    }
}

__global__ __launch_bounds__(256)
void scan_pass3(const float* __restrict__ delta, const float* __restrict__ u,
                const float* __restrict__ xdbl, const float* __restrict__ xz,
                const float* __restrict__ A_log, const float* __restrict__ D_skip,
                const float* __restrict__ Hin, _Float16* __restrict__ ygh)
{
    int gid = blockIdx.x * 256 + threadIdx.x;
    int n = gid & 15;
    int g = gid >> 4;
    if (g >= BATCH * CHUNKS * D_INNER) return;
    int d  = g & (D_INNER - 1);
    int bc = g >> 11;
    int c  = bc & (CHUNKS - 1);
    int b  = bc >> 4;

    float An = -__expf(A_log[d * D_STATE + n]);
    float Dd = D_skip[d];
    float h  = Hin[gid];

    const float* dp = delta + ((size_t)b * SEQ + c * LC) * D_INNER + d;
    const float* up = u     + ((size_t)b * SEQ + c * LC) * D_INNER + d;
    const float* xb = xdbl  + ((size_t)b * SEQ + c * LC) * 96;
    const float* rp = xz    + ((size_t)b * SEQ + c * LC) * (2 * D_INNER) + D_INNER + d;
    _Float16*    yp = ygh   + ((size_t)b * SEQ + c * LC) * 8192 + d;

    for (int l = 0; l < LC; ++l) {
        float dt = dp[(size_t)l * D_INNER];
        float ut = up[(size_t)l * D_INNER];
        float Bn = xb[l * 96 + DT_RANK + n];
        float Cn = xb[l * 96 + DT_RANK + D_STATE + n];

        h = __expf(dt * An) * h + dt * Bn * ut;
        float p = h * Cn;
        p += __shfl_xor(p, 1, 16);
        p += __shfl_xor(p, 2, 16);
        p += __shfl_xor(p, 4, 16);
        p += __shfl_xor(p, 8, 16);

        if (n == 0) {
            float res = rp[(size_t)l * (2 * D_INNER)];
            yp[(size_t)l * 8192] = (_Float16)((p + ut * Dd) * siluf(res));
        }
    }
}

// ---------------------------------------------------------------------------
extern "C" void kernel_launch(void* const* d_in, const int* in_sizes, int n_in,
                              void* d_out, int out_size, void* d_ws, size_t ws_size,
                              hipStream_t stream)
{
    const float* H      = (const float*)d_in[0];
    const float* Win    = (const float*)d_in[1];
    const float* convw  = (const float*)d_in[2];
    const float* convb  = (const float*)d_in[3];
    const float* xprojw = (const float*)d_in[4];
    const float* dtw    = (const float*)d_in[5];
    const float* dtb    = (const float*)d_in[6];
    const float* Alog   = (const float*)d_in[7];
    const float* Dskip  = (const float*)d_in[8];
    const float* Wout   = (const float*)d_in[9];
    float* out = (float*)d_out;

    float* ws    = (float*)d_ws;
    float* xz    = ws;                                   // [NTOK,4096] 32MB
    float* u     = xz   + (size_t)NTOK * 4096;           // 16MB
    float* xdbl  = u    + (size_t)NTOK * 2048;           // 0.75MB
    float* delta = xdbl + (size_t)NTOK * 96;             // 16MB
    float* Aprod = delta + (size_t)NTOK * 2048;          // 4MB
    float* Hend  = Aprod + (size_t)BATCH * CHUNKS * D_INNER * 16;  // 4MB

    // fp16 aliases (lifetime-disjoint with their hosts):
    _Float16* Hh    = (_Float16*)delta;                  // dead after GEMM1
    _Float16* Winp  = (_Float16*)delta + 2 * 1024 * 1024;// dead after GEMM1
    float*    part  = delta;                             // GEMM2 partials (12.6MB),
                                                         // dead once GEMM3 writes delta
    _Float16* ygh   = (_Float16*)xz;                     // stride 8192 (dead x-half)
    _Float16* Woutp = (_Float16*)Aprod;                  // Aprod dead after pass2

    dim3 blk(256);

    // 0a) Hh = fp16(H)
    f32_to_f16_k<<<(NTOK * D_MODEL / 4) / 256, blk, 0, stream>>>(H, Hh, NTOK * D_MODEL / 4);
    // 0b) Winp = pack(fp16(Win))
    pack_b_f16<4096><<<((D_MODEL / 8) * 4096) / 256, blk, 0, stream>>>(Win, Winp, D_MODEL);

    // 1) xz = H @ Win   (MFMA fp16)
    gemm_f16_mfma<<<dim3(4096 / 128, NTOK / 128), blk, 0, stream>>>(
        Hh, Winp, xz, 2 * D_INNER, D_MODEL, D_MODEL, 2 * D_INNER);

    // 2) u = silu(depthwise_conv(x) + b)
    conv_silu<<<(NTOK * D_INNER) / 256, blk, 0, stream>>>(xz, convw, convb, u);

    // 3) x_dbl = u @ x_proj_w  — split-K fp32 (grid z=16), then reduce
    gemm_f32_splitk<<<dim3(2, NTOK / 64, 16), blk, 0, stream>>>(
        u, xprojw, part, NTOK, 96, D_INNER, D_INNER, 96, 96);
    reduce_splitk<<<(NTOK * 96 + 255) / 256, blk, 0, stream>>>(
        part, xdbl, NTOK * 96, 16);

    // 4) delta = softplus(x_dbl[:, :64] @ dt_proj_w + dt_proj_b)  (fp32, K=64)
    gemm_f32<true, true><<<dim3(D_INNER / 64, NTOK / 64), blk, 0, stream>>>(
        xdbl, dtw, dtb, delta, NTOK, D_INNER, DT_RANK, 96, D_INNER, D_INNER);

    // 5) chunk-parallel scan
    {
        int nthr = BATCH * CHUNKS * D_INNER * 16;
        scan_pass1<<<nthr / 256, blk, 0, stream>>>(delta, u, xdbl, Alog, Aprod, Hend);
        scan_pass2<<<(BATCH * D_INNER * 16) / 256, blk, 0, stream>>>(Aprod, Hend);
        scan_pass3<<<nthr / 256, blk, 0, stream>>>(delta, u, xdbl, xz, Alog, Dskip,
                                                   Hend /*Hin*/, ygh);
    }

    // 5b) Woutp = pack(fp16(Wout))
    pack_b_f16<1024><<<((D_INNER / 8) * 1024) / 256, blk, 0, stream>>>(Wout, Woutp, D_INNER);

    // 6) out = yg @ Wout   (MFMA fp16; A stride 8192)
    gemm_f16_mfma<<<dim3(1024 / 128, NTOK / 128), blk, 0, stream>>>(
        ygh, Woutp, out, D_MODEL, D_INNER, 8192, D_MODEL);
}

// Round 7
// 347.735 us; speedup vs baseline: 3.8812x; 1.1296x over previous
//
#include <hip/hip_runtime.h>
#include <hip/hip_bf16.h>
#include <cstdint>

#define D_MODEL  1024
#define D_INNER  2048
#define D_STATE  16
#define DT_RANK  64
#define KERW     4
#define BATCH    2
#define SEQ      1024
#define NTOK     (BATCH * SEQ)
#define CHUNKS   16
#define LC       (SEQ / CHUNKS)     // 64 steps per chunk

typedef _Float16 h8 __attribute__((ext_vector_type(8)));
typedef _Float16 h4 __attribute__((ext_vector_type(4)));
typedef float    f32x4 __attribute__((ext_vector_type(4)));

__device__ __forceinline__ float siluf(float x) {
    return x / (1.f + __expf(-x));
}

#define GLOAD_LDS16(g, p) __builtin_amdgcn_global_load_lds( \
    (const __attribute__((address_space(1))) void*)(g),      \
    (__attribute__((address_space(3))) void*)(p), 16, 0, 0)

// ---------------------------------------------------------------------------
// fp32 -> fp16 elementwise (vectorized x4)
// ---------------------------------------------------------------------------
__global__ __launch_bounds__(256)
void f32_to_f16_k(const float* __restrict__ in, _Float16* __restrict__ out, int n4)
{
    int i = blockIdx.x * 256 + threadIdx.x;
    if (i >= n4) return;
    float4 v = ((const float4*)in)[i];
    h4 h = { (_Float16)v.x, (_Float16)v.y, (_Float16)v.z, (_Float16)v.w };
    *(h4*)(out + (size_t)i * 4) = h;
}

// ---------------------------------------------------------------------------
// Pack fp32 B[K][NN] row-major -> fp16 Bp[K/8][NN][8]
// ---------------------------------------------------------------------------
template<int NN>
__global__ __launch_bounds__(256)
void pack_b_f16(const float* __restrict__ B, _Float16* __restrict__ Bp, int K)
{
    constexpr int SH = (NN == 4096) ? 12 : 10;
    int gid = blockIdx.x * 256 + threadIdx.x;
    int n  = gid & (NN - 1);
    int kb = gid >> SH;
    h8 v;
    #pragma unroll
    for (int j = 0; j < 8; ++j)
        v[j] = (_Float16)B[(size_t)(kb * 8 + j) * NN + n];
    *(h8*)(Bp + (size_t)gid * 8) = v;
}

// ---------------------------------------------------------------------------
// fp16 MFMA GEMM: C[M,N] = A[M,K] @ B[K,N], fp32 out.
// 128x128 tile, BK=32, 4 waves (2x2), mfma_f32_16x16x32_f16.
// ---------------------------------------------------------------------------
__global__ __launch_bounds__(256)
void gemm_f16_mfma(const _Float16* __restrict__ A, const _Float16* __restrict__ Bp,
                   float* __restrict__ C, int N, int K, int lda, int ldc)
{
    __shared__ alignas(16) _Float16 As[4 * 128 * 8];   // 8 KB
    __shared__ alignas(16) _Float16 Bs[4 * 128 * 8];   // 8 KB

    const int tid = threadIdx.x;
    const int l = tid & 63, w = tid >> 6;
    const int wm = w >> 1, wn = w & 1;
    const int bm = blockIdx.y * 128, bn = blockIdx.x * 128;

    f32x4 acc[4][4] = {};

    const int kg = l >> 4, r = l & 15;

    for (int k0 = 0; k0 < K; k0 += 32) {
        #pragma unroll
        for (int i = 0; i < 2; ++i) {
            int c = i * 256 + w * 64 + l;
            int row = c & 127, kgc = c >> 7;
            const _Float16* g = A + (size_t)(bm + row) * lda + k0 + kgc * 8;
            GLOAD_LDS16(g, As + (size_t)(i * 256 + w * 64) * 8);
        }
        #pragma unroll
        for (int i = 0; i < 2; ++i) {
            int c = i * 256 + w * 64 + l;
            int col = c & 127, kgc = c >> 7;
            const _Float16* g = Bp + ((size_t)((k0 >> 3) + kgc) * N + bn + col) * 8;
            GLOAD_LDS16(g, Bs + (size_t)(i * 256 + w * 64) * 8);
        }
        __syncthreads();

        h8 a[4], b[4];
        #pragma unroll
        for (int mi = 0; mi < 4; ++mi)
            a[mi] = *(const h8*)(As + (size_t)(kg * 128 + wm * 64 + mi * 16 + r) * 8);
        #pragma unroll
        for (int ni = 0; ni < 4; ++ni)
            b[ni] = *(const h8*)(Bs + (size_t)(kg * 128 + wn * 64 + ni * 16 + r) * 8);

        #pragma unroll
        for (int mi = 0; mi < 4; ++mi)
            #pragma unroll
            for (int ni = 0; ni < 4; ++ni)
                acc[mi][ni] = __builtin_amdgcn_mfma_f32_16x16x32_f16(
                    a[mi], b[ni], acc[mi][ni], 0, 0, 0);

        __syncthreads();
    }

    const int q = l >> 4;
    #pragma unroll
    for (int mi = 0; mi < 4; ++mi)
        #pragma unroll
        for (int ni = 0; ni < 4; ++ni)
            #pragma unroll
            for (int j = 0; j < 4; ++j)
                C[(size_t)(bm + wm * 64 + mi * 16 + q * 4 + j) * ldc
                  + (bn + wn * 64 + ni * 16 + r)] = acc[mi][ni][j];
}

// ---------------------------------------------------------------------------
// Generic fp32 GEMM (used for GEMM3 only now): 64x64 tile.
// ---------------------------------------------------------------------------
template<bool BIAS, bool SOFTPLUS>
__global__ __launch_bounds__(256)
void gemm_f32(const float* __restrict__ A, const float* __restrict__ B,
              const float* __restrict__ bias, float* __restrict__ C,
              int M, int N, int K, int lda, int ldb, int ldc)
{
    __shared__ float As[16][68];
    __shared__ float Bs[16][68];
    const int tid = threadIdx.x;
    const int tx = tid & 15, ty = tid >> 4;
    const int bm = blockIdx.y * 64, bn = blockIdx.x * 64;

    float acc[4][4] = {};

    const int ar  = tid >> 2;
    const int ac4 = (tid & 3) << 2;
    const int bkr = tid >> 4;
    const int bc4 = (tid & 15) << 2;

    for (int k0 = 0; k0 < K; k0 += 16) {
        float4 av = make_float4(0.f, 0.f, 0.f, 0.f);
        {
            int row = bm + ar;
            if (row < M)
                av = *(const float4*)(A + (size_t)row * lda + (k0 + ac4));
        }
        As[ac4 + 0][ar] = av.x; As[ac4 + 1][ar] = av.y;
        As[ac4 + 2][ar] = av.z; As[ac4 + 3][ar] = av.w;

        float4 bv = make_float4(0.f, 0.f, 0.f, 0.f);
        {
            int col = bn + bc4;
            const float* bp = B + (size_t)(k0 + bkr) * ldb + col;
            if (col + 3 < N) {
                bv = *(const float4*)bp;
            } else {
                if (col + 0 < N) bv.x = bp[0];
                if (col + 1 < N) bv.y = bp[1];
                if (col + 2 < N) bv.z = bp[2];
                if (col + 3 < N) bv.w = bp[3];
            }
        }
        Bs[bkr][bc4 + 0] = bv.x; Bs[bkr][bc4 + 1] = bv.y;
        Bs[bkr][bc4 + 2] = bv.z; Bs[bkr][bc4 + 3] = bv.w;

        __syncthreads();

        #pragma unroll
        for (int kk = 0; kk < 16; ++kk) {
            float a[4], b[4];
            #pragma unroll
            for (int i = 0; i < 4; ++i) a[i] = As[kk][ty * 4 + i];
            #pragma unroll
            for (int j = 0; j < 4; ++j) b[j] = Bs[kk][tx * 4 + j];
            #pragma unroll
            for (int i = 0; i < 4; ++i)
                #pragma unroll
                for (int j = 0; j < 4; ++j)
                    acc[i][j] = fmaf(a[i], b[j], acc[i][j]);
        }
        __syncthreads();
    }

    #pragma unroll
    for (int i = 0; i < 4; ++i) {
        int row = bm + ty * 4 + i;
        if (row >= M) continue;
        #pragma unroll
        for (int j = 0; j < 4; ++j) {
            int col = bn + tx * 4 + j;
            if (col >= N) continue;
            float v = acc[i][j];
            if (BIAS) v += bias[col];
            if (SOFTPLUS) v = (v > 20.f) ? v : log1pf(__expf(v));
            C[(size_t)row * ldc + col] = v;
        }
    }
}

// ---------------------------------------------------------------------------
// Split-K fp32 GEMM for GEMM2 (M=2048, N=96, K=2048).
// ---------------------------------------------------------------------------
__global__ __launch_bounds__(256)
void gemm_f32_splitk(const float* __restrict__ A, const float* __restrict__ B,
                     float* __restrict__ part,
                     int M, int N, int K, int lda, int ldb, int ldc)
{
    __shared__ float As[16][68];
    __shared__ float Bs[16][68];
    const int tid = threadIdx.x;
    const int tx = tid & 15, ty = tid >> 4;
    const int bm = blockIdx.y * 64, bn = blockIdx.x * 64;
    const int kslice = K / gridDim.z;
    const int kbeg = blockIdx.z * kslice;

    float acc[4][4] = {};

    const int ar  = tid >> 2;
    const int ac4 = (tid & 3) << 2;
    const int bkr = tid >> 4;
    const int bc4 = (tid & 15) << 2;

    for (int k0 = kbeg; k0 < kbeg + kslice; k0 += 16) {
        float4 av;
        {
            int row = bm + ar;
            av = *(const float4*)(A + (size_t)row * lda + (k0 + ac4));
        }
        As[ac4 + 0][ar] = av.x; As[ac4 + 1][ar] = av.y;
        As[ac4 + 2][ar] = av.z; As[ac4 + 3][ar] = av.w;

        float4 bv = make_float4(0.f, 0.f, 0.f, 0.f);
        {
            int col = bn + bc4;
            const float* bp = B + (size_t)(k0 + bkr) * ldb + col;
            if (col + 3 < N) {
                bv = *(const float4*)bp;
            } else {
                if (col + 0 < N) bv.x = bp[0];
                if (col + 1 < N) bv.y = bp[1];
                if (col + 2 < N) bv.z = bp[2];
                if (col + 3 < N) bv.w = bp[3];
            }
        }
        Bs[bkr][bc4 + 0] = bv.x; Bs[bkr][bc4 + 1] = bv.y;
        Bs[bkr][bc4 + 2] = bv.z; Bs[bkr][bc4 + 3] = bv.w;

        __syncthreads();

        #pragma unroll
        for (int kk = 0; kk < 16; ++kk) {
            float a[4], b[4];
            #pragma unroll
            for (int i = 0; i < 4; ++i) a[i] = As[kk][ty * 4 + i];
            #pragma unroll
            for (int j = 0; j < 4; ++j) b[j] = Bs[kk][tx * 4 + j];
            #pragma unroll
            for (int i = 0; i < 4; ++i)
                #pragma unroll
                for (int j = 0; j < 4; ++j)
                    acc[i][j] = fmaf(a[i], b[j], acc[i][j]);
        }
        __syncthreads();
    }

    float* dst = part + (size_t)blockIdx.z * M * ldc;
    #pragma unroll
    for (int i = 0; i < 4; ++i) {
        int row = bm + ty * 4 + i;
        #pragma unroll
        for (int j = 0; j < 4; ++j) {
            int col = bn + tx * 4 + j;
            if (col >= N) continue;
            dst[(size_t)row * ldc + col] = acc[i][j];
        }
    }
}

__global__ __launch_bounds__(256)
void reduce_splitk(const float* __restrict__ part, float* __restrict__ out,
                   int n, int S)
{
    int i = blockIdx.x * 256 + threadIdx.x;
    if (i >= n) return;
    float s = 0.f;
    for (int j = 0; j < S; ++j) s += part[(size_t)j * n + i];
    out[i] = s;
}

// ---------------------------------------------------------------------------
// Depthwise causal conv (K=4) + bias + SiLU.
// ---------------------------------------------------------------------------
__global__ __launch_bounds__(256)
void conv_silu(const float* __restrict__ xz, const float* __restrict__ conv_w,
               const float* __restrict__ conv_b, float* __restrict__ u)
{
    int idx = blockIdx.x * 256 + threadIdx.x;
    if (idx >= NTOK * D_INNER) return;
    int d = idx & (D_INNER - 1);
    int t = idx >> 11;
    int l = t & (SEQ - 1);
    int b = t >> 10;

    float w0 = conv_w[d * 4 + 0], w1 = conv_w[d * 4 + 1];
    float w2 = conv_w[d * 4 + 2], w3 = conv_w[d * 4 + 3];

    const float* base = xz + (size_t)b * SEQ * (2 * D_INNER) + d;
    float acc = conv_b[d];
    if (l >= 3) acc += w0 * base[(size_t)(l - 3) * (2 * D_INNER)];
    if (l >= 2) acc += w1 * base[(size_t)(l - 2) * (2 * D_INNER)];
    if (l >= 1) acc += w2 * base[(size_t)(l - 1) * (2 * D_INNER)];
    acc += w3 * base[(size_t)l * (2 * D_INNER)];

    u[idx] = siluf(acc);
}

// ---------------------------------------------------------------------------
// Chunk-parallel selective scan — one thread per (b,chunk,d), 16 states in
// registers. No cross-lane ops; dt/u/res loads coalesced (consecutive d per
// lane); B/C rows wave-uniform (single broadcast transaction).
// State buffers laid out [b][c][d][16].
// ---------------------------------------------------------------------------
__global__ __launch_bounds__(256)
void scan_pass1(const float* __restrict__ delta, const float* __restrict__ u,
                const float* __restrict__ xdbl, const float* __restrict__ A_log,
                float* __restrict__ Aprod, float* __restrict__ Hend)
{
    int t = blockIdx.x * 256 + threadIdx.x;     // over B*CHUNKS*D
    if (t >= BATCH * CHUNKS * D_INNER) return;
    int d  = t & (D_INNER - 1);
    int bc = t >> 11;
    int c  = bc & (CHUNKS - 1);
    int b  = bc >> 4;

    float An[16];
    {
        const float4* a4 = (const float4*)(A_log + d * 16);
        #pragma unroll
        for (int q = 0; q < 4; ++q) {
            float4 v = a4[q];
            An[q * 4 + 0] = -__expf(v.x);
            An[q * 4 + 1] = -__expf(v.y);
            An[q * 4 + 2] = -__expf(v.z);
            An[q * 4 + 3] = -__expf(v.w);
        }
    }

    const float* dp = delta + ((size_t)b * SEQ + c * LC) * D_INNER + d;
    const float* up = u     + ((size_t)b * SEQ + c * LC) * D_INNER + d;
    const float* xb = xdbl  + ((size_t)b * SEQ + c * LC) * 96 + DT_RANK;

    float h[16], ap[16];
    #pragma unroll
    for (int n = 0; n < 16; ++n) { h[n] = 0.f; ap[n] = 1.f; }

    for (int l = 0; l < LC; ++l) {
        float dt = dp[(size_t)l * D_INNER];
        float ut = up[(size_t)l * D_INNER];
        const float4* b4 = (const float4*)(xb + l * 96);
        float4 B0 = b4[0], B1 = b4[1], B2 = b4[2], B3 = b4[3];
        float Bv[16] = { B0.x, B0.y, B0.z, B0.w, B1.x, B1.y, B1.z, B1.w,
                         B2.x, B2.y, B2.z, B2.w, B3.x, B3.y, B3.z, B3.w };
        float dtu = dt * ut;
        #pragma unroll
        for (int n = 0; n < 16; ++n) {
            float da = __expf(dt * An[n]);
            h[n]  = fmaf(da, h[n], dtu * Bv[n]);
            ap[n] *= da;
        }
    }

    float4* hp = (float4*)(Hend  + (size_t)t * 16);
    float4* pp = (float4*)(Aprod + (size_t)t * 16);
    #pragma unroll
    for (int q = 0; q < 4; ++q) {
        hp[q] = make_float4(h[q*4+0], h[q*4+1], h[q*4+2], h[q*4+3]);
        pp[q] = make_float4(ap[q*4+0], ap[q*4+1], ap[q*4+2], ap[q*4+3]);
    }
}

__global__ __launch_bounds__(256)
void scan_pass2(const float* __restrict__ Aprod, float* __restrict__ HendHin)
{
    int idx = blockIdx.x * 256 + threadIdx.x;      // (b*D + d)*16 + n
    if (idx >= BATCH * D_INNER * D_STATE) return;
    int n = idx & 15;
    int d = (idx >> 4) & (D_INNER - 1);
    int b = idx >> 15;

    float h = 0.f;
    for (int c = 0; c < CHUNKS; ++c) {
        size_t j = ((((size_t)b * CHUNKS + c) * D_INNER) + d) * 16 + n;
        float ap = Aprod[j];
        float he = HendHin[j];
        HendHin[j] = h;            // Hend -> Hin in place (read-before-write)
        h = ap * h + he;
    }
}

// pass 3: replay from Hin + C-proj + D-skip + silu(res) gate; writes fp16 yg
// (row stride 8192 halfs, lives in the dead x-half of the xz buffer).
__global__ __launch_bounds__(256)
void scan_pass3(const float* __restrict__ delta, const float* __restrict__ u,
                const float* __restrict__ xdbl, const float* __restrict__ xz,
                const float* __restrict__ A_log, const float* __restrict__ D_skip,
                const float* __restrict__ Hin, _Float16* __restrict__ ygh)
{
    int t = blockIdx.x * 256 + threadIdx.x;     // over B*CHUNKS*D
    if (t >= BATCH * CHUNKS * D_INNER) return;
    int d  = t & (D_INNER - 1);
    int bc = t >> 11;
    int c  = bc & (CHUNKS - 1);
    int b  = bc >> 4;

    float An[16];
    {
        const float4* a4 = (const float4*)(A_log + d * 16);
        #pragma unroll
        for (int q = 0; q < 4; ++q) {
            float4 v = a4[q];
            An[q * 4 + 0] = -__expf(v.x);
            An[q * 4 + 1] = -__expf(v.y);
            An[q * 4 + 2] = -__expf(v.z);
            An[q * 4 + 3] = -__expf(v.w);
        }
    }
    float Dd = D_skip[d];

    float h[16];
    {
        const float4* h4p = (const float4*)(Hin + (size_t)t * 16);
        #pragma unroll
        for (int q = 0; q < 4; ++q) {
            float4 v = h4p[q];
            h[q * 4 + 0] = v.x; h[q * 4 + 1] = v.y;
            h[q * 4 + 2] = v.z; h[q * 4 + 3] = v.w;
        }
    }

    const float* dp = delta + ((size_t)b * SEQ + c * LC) * D_INNER + d;
    const float* up = u     + ((size_t)b * SEQ + c * LC) * D_INNER + d;
    const float* xb = xdbl  + ((size_t)b * SEQ + c * LC) * 96 + DT_RANK;
    const float* rp = xz    + ((size_t)b * SEQ + c * LC) * (2 * D_INNER) + D_INNER + d;
    _Float16*    yp = ygh   + ((size_t)b * SEQ + c * LC) * 8192 + d;

    for (int l = 0; l < LC; ++l) {
        float dt = dp[(size_t)l * D_INNER];
        float ut = up[(size_t)l * D_INNER];
        float res = rp[(size_t)l * (2 * D_INNER)];
        const float4* b4 = (const float4*)(xb + l * 96);
        float4 B0 = b4[0], B1 = b4[1], B2 = b4[2], B3 = b4[3];
        float4 C0 = b4[4], C1 = b4[5], C2 = b4[6], C3 = b4[7];
        float Bv[16] = { B0.x, B0.y, B0.z, B0.w, B1.x, B1.y, B1.z, B1.w,
                         B2.x, B2.y, B2.z, B2.w, B3.x, B3.y, B3.z, B3.w };
        float Cv[16] = { C0.x, C0.y, C0.z, C0.w, C1.x, C1.y, C1.z, C1.w,
                         C2.x, C2.y, C2.z, C2.w, C3.x, C3.y, C3.z, C3.w };
        float dtu = dt * ut;
        float y = 0.f;
        #pragma unroll
        for (int n = 0; n < 16; ++n) {
            float da = __expf(dt * An[n]);
            h[n] = fmaf(da, h[n], dtu * Bv[n]);
            y = fmaf(h[n], Cv[n], y);
        }
        yp[(size_t)l * 8192] = (_Float16)((y + ut * Dd) * siluf(res));
    }
}

// ---------------------------------------------------------------------------
extern "C" void kernel_launch(void* const* d_in, const int* in_sizes, int n_in,
                              void* d_out, int out_size, void* d_ws, size_t ws_size,
                              hipStream_t stream)
{
    const float* H      = (const float*)d_in[0];
    const float* Win    = (const float*)d_in[1];
    const float* convw  = (const float*)d_in[2];
    const float* convb  = (const float*)d_in[3];
    const float* xprojw = (const float*)d_in[4];
    const float* dtw    = (const float*)d_in[5];
    const float* dtb    = (const float*)d_in[6];
    const float* Alog   = (const float*)d_in[7];
    const float* Dskip  = (const float*)d_in[8];
    const float* Wout   = (const float*)d_in[9];
    float* out = (float*)d_out;

    float* ws    = (float*)d_ws;
    float* xz    = ws;                                   // [NTOK,4096] 32MB
    float* u     = xz   + (size_t)NTOK * 4096;           // 16MB
    float* xdbl  = u    + (size_t)NTOK * 2048;           // 0.75MB
    float* delta = xdbl + (size_t)NTOK * 96;             // 16MB
    float* Aprod = delta + (size_t)NTOK * 2048;          // 4MB
    float* Hend  = Aprod + (size_t)BATCH * CHUNKS * D_INNER * 16;  // 4MB

    // fp16 aliases (lifetime-disjoint with their hosts):
    _Float16* Hh    = (_Float16*)delta;                  // dead after GEMM1
    _Float16* Winp  = (_Float16*)delta + 2 * 1024 * 1024;// dead after GEMM1
    float*    part  = delta;                             // GEMM2 partials (12.6MB),
                                                         // dead once GEMM3 writes delta
    _Float16* ygh   = (_Float16*)xz;                     // stride 8192 (dead x-half)
    _Float16* Woutp = (_Float16*)Aprod;                  // Aprod dead after pass2

    dim3 blk(256);

    // 0a) Hh = fp16(H)
    f32_to_f16_k<<<(NTOK * D_MODEL / 4) / 256, blk, 0, stream>>>(H, Hh, NTOK * D_MODEL / 4);
    // 0b) Winp = pack(fp16(Win))
    pack_b_f16<4096><<<((D_MODEL / 8) * 4096) / 256, blk, 0, stream>>>(Win, Winp, D_MODEL);

    // 1) xz = H @ Win   (MFMA fp16)
    gemm_f16_mfma<<<dim3(4096 / 128, NTOK / 128), blk, 0, stream>>>(
        Hh, Winp, xz, 2 * D_INNER, D_MODEL, D_MODEL, 2 * D_INNER);

    // 2) u = silu(depthwise_conv(x) + b)
    conv_silu<<<(NTOK * D_INNER) / 256, blk, 0, stream>>>(xz, convw, convb, u);

    // 3) x_dbl = u @ x_proj_w  — split-K fp32 (grid z=16), then reduce
    gemm_f32_splitk<<<dim3(2, NTOK / 64, 16), blk, 0, stream>>>(
        u, xprojw, part, NTOK, 96, D_INNER, D_INNER, 96, 96);
    reduce_splitk<<<(NTOK * 96 + 255) / 256, blk, 0, stream>>>(
        part, xdbl, NTOK * 96, 16);

    // 4) delta = softplus(x_dbl[:, :64] @ dt_proj_w + dt_proj_b)  (fp32, K=64)
    gemm_f32<true, true><<<dim3(D_INNER / 64, NTOK / 64), blk, 0, stream>>>(
        xdbl, dtw, dtb, delta, NTOK, D_INNER, DT_RANK, 96, D_INNER, D_INNER);

    // 5) chunk-parallel scan (d-parallel, 16 states per thread)
    {
        int nthr = BATCH * CHUNKS * D_INNER;             // 65,536
        scan_pass1<<<nthr / 256, blk, 0, stream>>>(delta, u, xdbl, Alog, Aprod, Hend);
        scan_pass2<<<(BATCH * D_INNER * 16) / 256, blk, 0, stream>>>(Aprod, Hend);
        scan_pass3<<<nthr / 256, blk, 0, stream>>>(delta, u, xdbl, xz, Alog, Dskip,
                                                   Hend /*Hin*/, ygh);
    }

    // 5b) Woutp = pack(fp16(Wout))
    pack_b_f16<1024><<<((D_INNER / 8) * 1024) / 256, blk, 0, stream>>>(Wout, Woutp, D_INNER);

    // 6) out = yg @ Wout   (MFMA fp16; A stride 8192)
    gemm_f16_mfma<<<dim3(1024 / 128, NTOK / 128), blk, 0, stream>>>(
        ygh, Woutp, out, D_MODEL, D_INNER, 8192, D_MODEL);
}

// Round 8
// 333.131 us; speedup vs baseline: 4.0514x; 1.0438x over previous
//
#include <hip/hip_runtime.h>
#include <hip/hip_bf16.h>
#include <cstdint>

#define D_MODEL  1024
#define D_INNER  2048
#define D_STATE  16
#define DT_RANK  64
#define KERW     4
#define BATCH    2
#define SEQ      1024
#define NTOK     (BATCH * SEQ)
#define CHUNKS   16
#define LC       (SEQ / CHUNKS)     // 64 steps per chunk

typedef _Float16 h8 __attribute__((ext_vector_type(8)));
typedef _Float16 h4 __attribute__((ext_vector_type(4)));
typedef float    f32x4 __attribute__((ext_vector_type(4)));

__device__ __forceinline__ float siluf(float x) {
    return x / (1.f + __expf(-x));
}

#define GLOAD_LDS16(g, p) __builtin_amdgcn_global_load_lds( \
    (const __attribute__((address_space(1))) void*)(g),      \
    (__attribute__((address_space(3))) void*)(p), 16, 0, 0)

// ---------------------------------------------------------------------------
// fp32 -> fp16 elementwise (vectorized x4)
// ---------------------------------------------------------------------------
__global__ __launch_bounds__(256)
void f32_to_f16_k(const float* __restrict__ in, _Float16* __restrict__ out, int n4)
{
    int i = blockIdx.x * 256 + threadIdx.x;
    if (i >= n4) return;
    float4 v = ((const float4*)in)[i];
    h4 h = { (_Float16)v.x, (_Float16)v.y, (_Float16)v.z, (_Float16)v.w };
    *(h4*)(out + (size_t)i * 4) = h;
}

// ---------------------------------------------------------------------------
// Pack fp32 B[K][NN] row-major -> fp16 Bp[K/8][NN][8]
// ---------------------------------------------------------------------------
template<int NN>
__global__ __launch_bounds__(256)
void pack_b_f16(const float* __restrict__ B, _Float16* __restrict__ Bp, int K)
{
    constexpr int SH = (NN == 4096) ? 12 : 10;
    int gid = blockIdx.x * 256 + threadIdx.x;
    int n  = gid & (NN - 1);
    int kb = gid >> SH;
    h8 v;
    #pragma unroll
    for (int j = 0; j < 8; ++j)
        v[j] = (_Float16)B[(size_t)(kb * 8 + j) * NN + n];
    *(h8*)(Bp + (size_t)gid * 8) = v;
}

// ---------------------------------------------------------------------------
// fp16 MFMA GEMM: C[M,N] = A[M,K] @ B[K,N], fp32 out.
// BM=128, BN=64, BK=32, 256 threads = 4 waves (2 wm x 2 wn, 64x32 each).
// 2-stage LDS double-buffer: STAGE(t+1) issued before compute(t) so the
// barrier's vmcnt-drain lands after the MFMAs. Bijective XCD swizzle on a
// 1-D x-grid (requires gridDim.x % 8 == 0). Optional split-K via gridDim.z:
// partial z writes C + z*M*ldc (fp32 reduce afterwards).
// ---------------------------------------------------------------------------
__device__ __forceinline__ void stage_tiles(
    const _Float16* __restrict__ A, const _Float16* __restrict__ Bp,
    _Float16* as, _Float16* bs, int bm, int bn, int k0, int N, int lda, int tid)
{
    // A tile: 128 rows x 32 k = 512 chunks of 16B; chunk c = tid + i*256
    #pragma unroll
    for (int i = 0; i < 2; ++i) {
        int c = i * 256 + tid;
        int row = c & 127, kgc = c >> 7;
        const _Float16* g = A + (size_t)(bm + row) * lda + k0 + kgc * 8;
        GLOAD_LDS16(g, as + (size_t)c * 8);
    }
    // B tile: 64 cols x 32 k = 256 chunks; chunk c = tid
    {
        int c = tid;
        int col = c & 63, kgc = c >> 6;
        const _Float16* g = Bp + ((size_t)((k0 >> 3) + kgc) * N + bn + col) * 8;
        GLOAD_LDS16(g, bs + (size_t)c * 8);
    }
}

__global__ __launch_bounds__(256)
void gemm_f16_mfma(const _Float16* __restrict__ A, const _Float16* __restrict__ Bp,
                   float* __restrict__ C, int M, int N, int K, int lda, int ldc)
{
    __shared__ alignas(16) _Float16 As[2][4 * 128 * 8];   // 2 x 8 KB
    __shared__ alignas(16) _Float16 Bs[2][4 * 64 * 8];    // 2 x 4 KB

    const int tid = threadIdx.x;
    const int l = tid & 63, w = tid >> 6;
    const int wm = w >> 1, wn = w & 1;          // 2x2 waves, 64x32 each

    // bijective XCD-chunk swizzle (gridDim.x % 8 == 0)
    const int nwg = gridDim.x;
    const int qch = nwg >> 3;
    const int wg  = ((blockIdx.x & 7) * qch) + (blockIdx.x >> 3);
    const int nbn = N >> 6;
    const int bn  = (wg % nbn) * 64;
    const int bm  = (wg / nbn) * 128;

    const int kslice = K / gridDim.z;
    const int kbeg = blockIdx.z * kslice;
    const int kend = kbeg + kslice;

    f32x4 acc[4][2] = {};
    const int kg = l >> 4, r = l & 15;

    stage_tiles(A, Bp, As[0], Bs[0], bm, bn, kbeg, N, lda, tid);
    __syncthreads();                            // compiler drains vmcnt(0)

    int cur = 0;
    for (int k0 = kbeg; k0 < kend; k0 += 32) {
        if (k0 + 32 < kend)
            stage_tiles(A, Bp, As[cur ^ 1], Bs[cur ^ 1], bm, bn, k0 + 32, N, lda, tid);

        h8 a[4], b[2];
        #pragma unroll
        for (int mi = 0; mi < 4; ++mi)
            a[mi] = *(const h8*)(As[cur] + (size_t)(kg * 128 + wm * 64 + mi * 16 + r) * 8);
        #pragma unroll
        for (int ni = 0; ni < 2; ++ni)
            b[ni] = *(const h8*)(Bs[cur] + (size_t)(kg * 64 + wn * 32 + ni * 16 + r) * 8);

        #pragma unroll
        for (int mi = 0; mi < 4; ++mi)
            #pragma unroll
            for (int ni = 0; ni < 2; ++ni)
                acc[mi][ni] = __builtin_amdgcn_mfma_f32_16x16x32_f16(
                    a[mi], b[ni], acc[mi][ni], 0, 0, 0);

        __syncthreads();
        cur ^= 1;
    }

    // C/D layout: col = lane&15, row = (lane>>4)*4 + reg  [m89-verified]
    float* dst = C + (size_t)blockIdx.z * M * ldc;
    const int q = l >> 4;
    #pragma unroll
    for (int mi = 0; mi < 4; ++mi)
        #pragma unroll
        for (int ni = 0; ni < 2; ++ni)
            #pragma unroll
            for (int j = 0; j < 4; ++j)
                dst[(size_t)(bm + wm * 64 + mi * 16 + q * 4 + j) * ldc
                    + (bn + wn * 32 + ni * 16 + r)] = acc[mi][ni][j];
}

// ---------------------------------------------------------------------------
// Generic fp32 GEMM (used for GEMM3 only): 64x64 tile.
// ---------------------------------------------------------------------------
template<bool BIAS, bool SOFTPLUS>
__global__ __launch_bounds__(256)
void gemm_f32(const float* __restrict__ A, const float* __restrict__ B,
              const float* __restrict__ bias, float* __restrict__ C,
              int M, int N, int K, int lda, int ldb, int ldc)
{
    __shared__ float As[16][68];
    __shared__ float Bs[16][68];
    const int tid = threadIdx.x;
    const int tx = tid & 15, ty = tid >> 4;
    const int bm = blockIdx.y * 64, bn = blockIdx.x * 64;

    float acc[4][4] = {};

    const int ar  = tid >> 2;
    const int ac4 = (tid & 3) << 2;
    const int bkr = tid >> 4;
    const int bc4 = (tid & 15) << 2;

    for (int k0 = 0; k0 < K; k0 += 16) {
        float4 av = make_float4(0.f, 0.f, 0.f, 0.f);
        {
            int row = bm + ar;
            if (row < M)
                av = *(const float4*)(A + (size_t)row * lda + (k0 + ac4));
        }
        As[ac4 + 0][ar] = av.x; As[ac4 + 1][ar] = av.y;
        As[ac4 + 2][ar] = av.z; As[ac4 + 3][ar] = av.w;

        float4 bv = make_float4(0.f, 0.f, 0.f, 0.f);
        {
            int col = bn + bc4;
            const float* bp = B + (size_t)(k0 + bkr) * ldb + col;
            if (col + 3 < N) {
                bv = *(const float4*)bp;
            } else {
                if (col + 0 < N) bv.x = bp[0];
                if (col + 1 < N) bv.y = bp[1];
                if (col + 2 < N) bv.z = bp[2];
                if (col + 3 < N) bv.w = bp[3];
            }
        }
        Bs[bkr][bc4 + 0] = bv.x; Bs[bkr][bc4 + 1] = bv.y;
        Bs[bkr][bc4 + 2] = bv.z; Bs[bkr][bc4 + 3] = bv.w;

        __syncthreads();

        #pragma unroll
        for (int kk = 0; kk < 16; ++kk) {
            float a[4], b[4];
            #pragma unroll
            for (int i = 0; i < 4; ++i) a[i] = As[kk][ty * 4 + i];
            #pragma unroll
            for (int j = 0; j < 4; ++j) b[j] = Bs[kk][tx * 4 + j];
            #pragma unroll
            for (int i = 0; i < 4; ++i)
                #pragma unroll
                for (int j = 0; j < 4; ++j)
                    acc[i][j] = fmaf(a[i], b[j], acc[i][j]);
        }
        __syncthreads();
    }

    #pragma unroll
    for (int i = 0; i < 4; ++i) {
        int row = bm + ty * 4 + i;
        if (row >= M) continue;
        #pragma unroll
        for (int j = 0; j < 4; ++j) {
            int col = bn + tx * 4 + j;
            if (col >= N) continue;
            float v = acc[i][j];
            if (BIAS) v += bias[col];
            if (SOFTPLUS) v = (v > 20.f) ? v : log1pf(__expf(v));
            C[(size_t)row * ldc + col] = v;
        }
    }
}

// ---------------------------------------------------------------------------
// Split-K fp32 GEMM for GEMM2 (M=2048, N=96, K=2048).
// ---------------------------------------------------------------------------
__global__ __launch_bounds__(256)
void gemm_f32_splitk(const float* __restrict__ A, const float* __restrict__ B,
                     float* __restrict__ part,
                     int M, int N, int K, int lda, int ldb, int ldc)
{
    __shared__ float As[16][68];
    __shared__ float Bs[16][68];
    const int tid = threadIdx.x;
    const int tx = tid & 15, ty = tid >> 4;
    const int bm = blockIdx.y * 64, bn = blockIdx.x * 64;
    const int kslice = K / gridDim.z;
    const int kbeg = blockIdx.z * kslice;

    float acc[4][4] = {};

    const int ar  = tid >> 2;
    const int ac4 = (tid & 3) << 2;
    const int bkr = tid >> 4;
    const int bc4 = (tid & 15) << 2;

    for (int k0 = kbeg; k0 < kbeg + kslice; k0 += 16) {
        float4 av;
        {
            int row = bm + ar;
            av = *(const float4*)(A + (size_t)row * lda + (k0 + ac4));
        }
        As[ac4 + 0][ar] = av.x; As[ac4 + 1][ar] = av.y;
        As[ac4 + 2][ar] = av.z; As[ac4 + 3][ar] = av.w;

        float4 bv = make_float4(0.f, 0.f, 0.f, 0.f);
        {
            int col = bn + bc4;
            const float* bp = B + (size_t)(k0 + bkr) * ldb + col;
            if (col + 3 < N) {
                bv = *(const float4*)bp;
            } else {
                if (col + 0 < N) bv.x = bp[0];
                if (col + 1 < N) bv.y = bp[1];
                if (col + 2 < N) bv.z = bp[2];
                if (col + 3 < N) bv.w = bp[3];
            }
        }
        Bs[bkr][bc4 + 0] = bv.x; Bs[bkr][bc4 + 1] = bv.y;
        Bs[bkr][bc4 + 2] = bv.z; Bs[bkr][bc4 + 3] = bv.w;

        __syncthreads();

        #pragma unroll
        for (int kk = 0; kk < 16; ++kk) {
            float a[4], b[4];
            #pragma unroll
            for (int i = 0; i < 4; ++i) a[i] = As[kk][ty * 4 + i];
            #pragma unroll
            for (int j = 0; j < 4; ++j) b[j] = Bs[kk][tx * 4 + j];
            #pragma unroll
            for (int i = 0; i < 4; ++i)
                #pragma unroll
                for (int j = 0; j < 4; ++j)
                    acc[i][j] = fmaf(a[i], b[j], acc[i][j]);
        }
        __syncthreads();
    }

    float* dst = part + (size_t)blockIdx.z * M * ldc;
    #pragma unroll
    for (int i = 0; i < 4; ++i) {
        int row = bm + ty * 4 + i;
        #pragma unroll
        for (int j = 0; j < 4; ++j) {
            int col = bn + tx * 4 + j;
            if (col >= N) continue;
            dst[(size_t)row * ldc + col] = acc[i][j];
        }
    }
}

__global__ __launch_bounds__(256)
void reduce_splitk(const float* __restrict__ part, float* __restrict__ out,
                   int n, int S)
{
    int i = blockIdx.x * 256 + threadIdx.x;
    if (i >= n) return;
    float s = 0.f;
    for (int j = 0; j < S; ++j) s += part[(size_t)j * n + i];
    out[i] = s;
}

// ---------------------------------------------------------------------------
// Depthwise causal conv (K=4) + bias + SiLU.
// ---------------------------------------------------------------------------
__global__ __launch_bounds__(256)
void conv_silu(const float* __restrict__ xz, const float* __restrict__ conv_w,
               const float* __restrict__ conv_b, float* __restrict__ u)
{
    int idx = blockIdx.x * 256 + threadIdx.x;
    if (idx >= NTOK * D_INNER) return;
    int d = idx & (D_INNER - 1);
    int t = idx >> 11;
    int l = t & (SEQ - 1);
    int b = t >> 10;

    float w0 = conv_w[d * 4 + 0], w1 = conv_w[d * 4 + 1];
    float w2 = conv_w[d * 4 + 2], w3 = conv_w[d * 4 + 3];

    const float* base = xz + (size_t)b * SEQ * (2 * D_INNER) + d;
    float acc = conv_b[d];
    if (l >= 3) acc += w0 * base[(size_t)(l - 3) * (2 * D_INNER)];
    if (l >= 2) acc += w1 * base[(size_t)(l - 2) * (2 * D_INNER)];
    if (l >= 1) acc += w2 * base[(size_t)(l - 1) * (2 * D_INNER)];
    acc += w3 * base[(size_t)l * (2 * D_INNER)];

    u[idx] = siluf(acc);
}

// ---------------------------------------------------------------------------
// Chunk-parallel selective scan — one thread per (b,chunk,d), 16 states in
// registers. State buffers laid out [b][c][d][16].
// ---------------------------------------------------------------------------
__global__ __launch_bounds__(256)
void scan_pass1(const float* __restrict__ delta, const float* __restrict__ u,
                const float* __restrict__ xdbl, const float* __restrict__ A_log,
                float* __restrict__ Aprod, float* __restrict__ Hend)
{
    int t = blockIdx.x * 256 + threadIdx.x;     // over B*CHUNKS*D
    if (t >= BATCH * CHUNKS * D_INNER) return;
    int d  = t & (D_INNER - 1);
    int bc = t >> 11;
    int c  = bc & (CHUNKS - 1);
    int b  = bc >> 4;

    float An[16];
    {
        const float4* a4 = (const float4*)(A_log + d * 16);
        #pragma unroll
        for (int q = 0; q < 4; ++q) {
            float4 v = a4[q];
            An[q * 4 + 0] = -__expf(v.x);
            An[q * 4 + 1] = -__expf(v.y);
            An[q * 4 + 2] = -__expf(v.z);
            An[q * 4 + 3] = -__expf(v.w);
        }
    }

    const float* dp = delta + ((size_t)b * SEQ + c * LC) * D_INNER + d;
    const float* up = u     + ((size_t)b * SEQ + c * LC) * D_INNER + d;
    const float* xb = xdbl  + ((size_t)b * SEQ + c * LC) * 96 + DT_RANK;

    float h[16], ap[16];
    #pragma unroll
    for (int n = 0; n < 16; ++n) { h[n] = 0.f; ap[n] = 1.f; }

    for (int l = 0; l < LC; ++l) {
        float dt = dp[(size_t)l * D_INNER];
        float ut = up[(size_t)l * D_INNER];
        const float4* b4 = (const float4*)(xb + l * 96);
        float4 B0 = b4[0], B1 = b4[1], B2 = b4[2], B3 = b4[3];
        float Bv[16] = { B0.x, B0.y, B0.z, B0.w, B1.x, B1.y, B1.z, B1.w,
                         B2.x, B2.y, B2.z, B2.w, B3.x, B3.y, B3.z, B3.w };
        float dtu = dt * ut;
        #pragma unroll
        for (int n = 0; n < 16; ++n) {
            float da = __expf(dt * An[n]);
            h[n]  = fmaf(da, h[n], dtu * Bv[n]);
            ap[n] *= da;
        }
    }

    float4* hp = (float4*)(Hend  + (size_t)t * 16);
    float4* pp = (float4*)(Aprod + (size_t)t * 16);
    #pragma unroll
    for (int q = 0; q < 4; ++q) {
        hp[q] = make_float4(h[q*4+0], h[q*4+1], h[q*4+2], h[q*4+3]);
        pp[q] = make_float4(ap[q*4+0], ap[q*4+1], ap[q*4+2], ap[q*4+3]);
    }
}

__global__ __launch_bounds__(256)
void scan_pass2(const float* __restrict__ Aprod, float* __restrict__ HendHin)
{
    int idx = blockIdx.x * 256 + threadIdx.x;      // (b*D + d)*16 + n
    if (idx >= BATCH * D_INNER * D_STATE) return;
    int n = idx & 15;
    int d = (idx >> 4) & (D_INNER - 1);
    int b = idx >> 15;

    float h = 0.f;
    for (int c = 0; c < CHUNKS; ++c) {
        size_t j = ((((size_t)b * CHUNKS + c) * D_INNER) + d) * 16 + n;
        float ap = Aprod[j];
        float he = HendHin[j];
        HendHin[j] = h;            // Hend -> Hin in place (read-before-write)
        h = ap * h + he;
    }
}

// pass 3: replay from Hin + C-proj + D-skip + silu(res) gate; writes fp16 yg
// (row stride 8192 halfs, lives in the dead x-half of the xz buffer).
__global__ __launch_bounds__(256)
void scan_pass3(const float* __restrict__ delta, const float* __restrict__ u,
                const float* __restrict__ xdbl, const float* __restrict__ xz,
                const float* __restrict__ A_log, const float* __restrict__ D_skip,
                const float* __restrict__ Hin, _Float16* __restrict__ ygh)
{
    int t = blockIdx.x * 256 + threadIdx.x;     // over B*CHUNKS*D
    if (t >= BATCH * CHUNKS * D_INNER) return;
    int d  = t & (D_INNER - 1);
    int bc = t >> 11;
    int c  = bc & (CHUNKS - 1);
    int b  = bc >> 4;

    float An[16];
    {
        const float4* a4 = (const float4*)(A_log + d * 16);
        #pragma unroll
        for (int q = 0; q < 4; ++q) {
            float4 v = a4[q];
            An[q * 4 + 0] = -__expf(v.x);
            An[q * 4 + 1] = -__expf(v.y);
            An[q * 4 + 2] = -__expf(v.z);
            An[q * 4 + 3] = -__expf(v.w);
        }
    }
    float Dd = D_skip[d];

    float h[16];
    {
        const float4* h4p = (const float4*)(Hin + (size_t)t * 16);
        #pragma unroll
        for (int q = 0; q < 4; ++q) {
            float4 v = h4p[q];
            h[q * 4 + 0] = v.x; h[q * 4 + 1] = v.y;
            h[q * 4 + 2] = v.z; h[q * 4 + 3] = v.w;
        }
    }

    const float* dp = delta + ((size_t)b * SEQ + c * LC) * D_INNER + d;
    const float* up = u     + ((size_t)b * SEQ + c * LC) * D_INNER + d;
    const float* xb = xdbl  + ((size_t)b * SEQ + c * LC) * 96 + DT_RANK;
    const float* rp = xz    + ((size_t)b * SEQ + c * LC) * (2 * D_INNER) + D_INNER + d;
    _Float16*    yp = ygh   + ((size_t)b * SEQ + c * LC) * 8192 + d;

    for (int l = 0; l < LC; ++l) {
        float dt = dp[(size_t)l * D_INNER];
        float ut = up[(size_t)l * D_INNER];
        float res = rp[(size_t)l * (2 * D_INNER)];
        const float4* b4 = (const float4*)(xb + l * 96);
        float4 B0 = b4[0], B1 = b4[1], B2 = b4[2], B3 = b4[3];
        float4 C0 = b4[4], C1 = b4[5], C2 = b4[6], C3 = b4[7];
        float Bv[16] = { B0.x, B0.y, B0.z, B0.w, B1.x, B1.y, B1.z, B1.w,
                         B2.x, B2.y, B2.z, B2.w, B3.x, B3.y, B3.z, B3.w };
        float Cv[16] = { C0.x, C0.y, C0.z, C0.w, C1.x, C1.y, C1.z, C1.w,
                         C2.x, C2.y, C2.z, C2.w, C3.x, C3.y, C3.z, C3.w };
        float dtu = dt * ut;
        float y = 0.f;
        #pragma unroll
        for (int n = 0; n < 16; ++n) {
            float da = __expf(dt * An[n]);
            h[n] = fmaf(da, h[n], dtu * Bv[n]);
            y = fmaf(h[n], Cv[n], y);
        }
        yp[(size_t)l * 8192] = (_Float16)((y + ut * Dd) * siluf(res));
    }
}

// ---------------------------------------------------------------------------
extern "C" void kernel_launch(void* const* d_in, const int* in_sizes, int n_in,
                              void* d_out, int out_size, void* d_ws, size_t ws_size,
                              hipStream_t stream)
{
    const float* H      = (const float*)d_in[0];
    const float* Win    = (const float*)d_in[1];
    const float* convw  = (const float*)d_in[2];
    const float* convb  = (const float*)d_in[3];
    const float* xprojw = (const float*)d_in[4];
    const float* dtw    = (const float*)d_in[5];
    const float* dtb    = (const float*)d_in[6];
    const float* Alog   = (const float*)d_in[7];
    const float* Dskip  = (const float*)d_in[8];
    const float* Wout   = (const float*)d_in[9];
    float* out = (float*)d_out;

    float* ws    = (float*)d_ws;
    float* xz    = ws;                                   // [NTOK,4096] 32MB
    float* u     = xz   + (size_t)NTOK * 4096;           // 16MB
    float* xdbl  = u    + (size_t)NTOK * 2048;           // 0.75MB
    float* delta = xdbl + (size_t)NTOK * 96;             // 16MB
    float* Aprod = delta + (size_t)NTOK * 2048;          // 4MB
    float* Hend  = Aprod + (size_t)BATCH * CHUNKS * D_INNER * 16;  // 4MB

    // fp16 / fp32 aliases (lifetime-disjoint with their hosts):
    _Float16* Hh    = (_Float16*)delta;                  // dead after GEMM1
    _Float16* Winp  = (_Float16*)delta + 2 * 1024 * 1024;// dead after GEMM1
    float*    part  = delta;                             // GEMM2 partials (12.6MB)
    float*    part4 = delta;                             // GEMM4 partials (2 x 8MB),
                                                         // delta dead after pass3
    _Float16* ygh   = (_Float16*)xz;                     // stride 8192 (dead x-half)
    _Float16* Woutp = (_Float16*)Aprod;                  // Aprod dead after pass2

    dim3 blk(256);

    // 0a) Hh = fp16(H)
    f32_to_f16_k<<<(NTOK * D_MODEL / 4) / 256, blk, 0, stream>>>(H, Hh, NTOK * D_MODEL / 4);
    // 0b) Winp = pack(fp16(Win))
    pack_b_f16<4096><<<((D_MODEL / 8) * 4096) / 256, blk, 0, stream>>>(Win, Winp, D_MODEL);

    // 1) xz = H @ Win   (MFMA fp16; 64x16 -> 1024 wg, z=1)
    gemm_f16_mfma<<<dim3((4096 / 64) * (NTOK / 128), 1, 1), blk, 0, stream>>>(
        Hh, Winp, xz, NTOK, 2 * D_INNER, D_MODEL, D_MODEL, 2 * D_INNER);

    // 2) u = silu(depthwise_conv(x) + b)
    conv_silu<<<(NTOK * D_INNER) / 256, blk, 0, stream>>>(xz, convw, convb, u);

    // 3) x_dbl = u @ x_proj_w  — split-K fp32 (grid z=16), then reduce
    gemm_f32_splitk<<<dim3(2, NTOK / 64, 16), blk, 0, stream>>>(
        u, xprojw, part, NTOK, 96, D_INNER, D_INNER, 96, 96);
    reduce_splitk<<<(NTOK * 96 + 255) / 256, blk, 0, stream>>>(
        part, xdbl, NTOK * 96, 16);

    // 4) delta = softplus(x_dbl[:, :64] @ dt_proj_w + dt_proj_b)  (fp32, K=64)
    gemm_f32<true, true><<<dim3(D_INNER / 64, NTOK / 64), blk, 0, stream>>>(
        xdbl, dtw, dtb, delta, NTOK, D_INNER, DT_RANK, 96, D_INNER, D_INNER);

    // 5) chunk-parallel scan (d-parallel, 16 states per thread)
    {
        int nthr = BATCH * CHUNKS * D_INNER;             // 65,536
        scan_pass1<<<nthr / 256, blk, 0, stream>>>(delta, u, xdbl, Alog, Aprod, Hend);
        scan_pass2<<<(BATCH * D_INNER * 16) / 256, blk, 0, stream>>>(Aprod, Hend);
        scan_pass3<<<nthr / 256, blk, 0, stream>>>(delta, u, xdbl, xz, Alog, Dskip,
                                                   Hend /*Hin*/, ygh);
    }

    // 5b) Woutp = pack(fp16(Wout))
    pack_b_f16<1024><<<((D_INNER / 8) * 1024) / 256, blk, 0, stream>>>(Wout, Woutp, D_INNER);

    // 6) out = yg @ Wout   (MFMA fp16; A stride 8192; split-K=2 -> 512 wg)
    gemm_f16_mfma<<<dim3((1024 / 64) * (NTOK / 128), 1, 2), blk, 0, stream>>>(
        ygh, Woutp, part4, NTOK, D_MODEL, D_INNER, 8192, D_MODEL);
    reduce_splitk<<<(NTOK * D_MODEL) / 256, blk, 0, stream>>>(
        part4, out, NTOK * D_MODEL, 2);
}